// Round 1
// baseline (1322.989 us; speedup 1.0000x reference)
//
#include <hip/hip_runtime.h>

#define NUMH 2
#define BATCH 8
#define CCH 512
#define HWN 1024
#define BK 16
#define LDP 68   // padded LDS stride (68 mod 32 = 4 -> 2-way max on our patterns, 16B-aligned rows)

__device__ inline float waveReduceSum(float v) {
    #pragma unroll
    for (int off = 32; off > 0; off >>= 1) v += __shfl_xor(v, off);
    return v;
}
__device__ inline float waveReduceMax(float v) {
    #pragma unroll
    for (int off = 32; off > 0; off >>= 1) v = fmaxf(v, __shfl_xor(v, off));
    return v;
}

__global__ void zero_means_kernel(float* means) {
    if (threadIdx.x < 4) means[threadIdx.x] = 0.0f;
}

// ---------- projections: out[o][n] = sum_c W[o][c] * X[c][n] + bias[o]
// grid: x = n-tiles (16), y = o-tiles (8), z = p*16 + i*8 + b  (p: 0=Q,1=K,2=V)
__global__ __launch_bounds__(256) void proj_kernel(
    const float* __restrict__ fsrc, const float* __restrict__ ftgt,
    const float* __restrict__ Wq, const float* __restrict__ bq,
    const float* __restrict__ Wk, const float* __restrict__ bk,
    const float* __restrict__ Wv, const float* __restrict__ bv,
    float* __restrict__ Qt, float* __restrict__ Kp, float* __restrict__ Vp)
{
    __shared__ __align__(16) float a_s[BK][LDP];  // W^T tile: a_s[k][o]
    __shared__ __align__(16) float b_s[BK][LDP];  // X tile:  b_s[k][n]
    const int z = blockIdx.z;
    const int b = z & 7, i = (z >> 3) & 1, p = z >> 4;
    const float* W    = (p == 0 ? Wq : (p == 1 ? Wk : Wv)) + (size_t)i * CCH * CCH;
    const float* bias = (p == 0 ? bq : (p == 1 ? bk : bv)) + (size_t)i * CCH;
    const float* X    = (p == 1 ? fsrc : ftgt) + (size_t)(i * BATCH + b) * CCH * HWN;
    float* outp = (p == 0 ? Qt : (p == 1 ? Kp : Vp)) + (size_t)(i * BATCH + b) * CCH * HWN;

    const int tile_n = blockIdx.x * 64;
    const int tile_o = blockIdx.y * 64;
    const int t = threadIdx.x;
    const int tx = t & 15, ty = t >> 4;

    float acc[4][4] = {};
    for (int k0 = 0; k0 < CCH; k0 += BK) {
        {   // W tile -> a_s[k][o] (transpose on store; padded stride avoids conflicts)
            const int col = t & 15;          // k
            const int rowb = t >> 4;         // o base
            #pragma unroll
            for (int r = 0; r < 4; r++) {
                const int o = rowb + r * 16;
                a_s[col][o] = W[(size_t)(tile_o + o) * CCH + k0 + col];
            }
        }
        {   // X tile -> b_s[k][n], coalesced 256B rows
            const int col = t & 63;
            const int rb = t >> 6;
            #pragma unroll
            for (int r = 0; r < 4; r++) {
                const int k = rb + r * 4;
                b_s[k][col] = X[(size_t)(k0 + k) * HWN + tile_n + col];
            }
        }
        __syncthreads();
        #pragma unroll
        for (int k = 0; k < BK; k++) {
            const float4 av  = *(const float4*)&a_s[k][ty * 4];
            const float4 bv4 = *(const float4*)&b_s[k][tx * 4];
            const float ar[4] = {av.x, av.y, av.z, av.w};
            const float br[4] = {bv4.x, bv4.y, bv4.z, bv4.w};
            #pragma unroll
            for (int pp = 0; pp < 4; pp++)
                #pragma unroll
                for (int qq = 0; qq < 4; qq++)
                    acc[pp][qq] = fmaf(ar[pp], br[qq], acc[pp][qq]);
        }
        __syncthreads();
    }
    #pragma unroll
    for (int pp = 0; pp < 4; pp++) {
        const int o = tile_o + ty * 4 + pp;
        const float bia = bias[o];
        float4 v = {acc[pp][0] + bia, acc[pp][1] + bia, acc[pp][2] + bia, acc[pp][3] + bia};
        *(float4*)&outp[(size_t)o * HWN + tile_n + tx * 4] = v;
    }
}

// ---------- energy GEMM: E[n][m] = sum_c Qt[c][n] * Kp[c][m]; accumulate tile sums for means
// grid: x = m-tiles (16), y = n-tiles (16), z = i*Bc + bb
__global__ __launch_bounds__(256) void gemmE_kernel(
    const float* __restrict__ Qt, const float* __restrict__ Kp,
    float* __restrict__ E, float* __restrict__ means,
    int j, int b0, int Bc)
{
    __shared__ __align__(16) float a_s[BK][LDP];  // Qt tile [k][n]
    __shared__ __align__(16) float b_s[BK][LDP];  // Kp tile [k][m]
    __shared__ float red[4];
    const int z = blockIdx.z;
    const int i = z / Bc, bb = z % Bc, b = b0 + bb;
    const float* A  = Qt + (size_t)(i * BATCH + b) * CCH * HWN;
    const float* Bm = Kp + (size_t)(j * BATCH + b) * CCH * HWN;
    float* Eo = E + (size_t)(i * Bc + bb) * HWN * HWN;
    const int tile_m = blockIdx.x * 64;
    const int tile_n = blockIdx.y * 64;
    const int t = threadIdx.x;
    const int tx = t & 15, ty = t >> 4;

    float acc[4][4] = {};
    for (int k0 = 0; k0 < CCH; k0 += BK) {
        const int col = t & 63;
        const int rb = t >> 6;
        #pragma unroll
        for (int r = 0; r < 4; r++) {
            const int k = rb + r * 4;
            a_s[k][col] = A [(size_t)(k0 + k) * HWN + tile_n + col];
            b_s[k][col] = Bm[(size_t)(k0 + k) * HWN + tile_m + col];
        }
        __syncthreads();
        #pragma unroll
        for (int k = 0; k < BK; k++) {
            const float4 av  = *(const float4*)&a_s[k][ty * 4];
            const float4 bv4 = *(const float4*)&b_s[k][tx * 4];
            const float ar[4] = {av.x, av.y, av.z, av.w};
            const float br[4] = {bv4.x, bv4.y, bv4.z, bv4.w};
            #pragma unroll
            for (int pp = 0; pp < 4; pp++)
                #pragma unroll
                for (int qq = 0; qq < 4; qq++)
                    acc[pp][qq] = fmaf(ar[pp], br[qq], acc[pp][qq]);
        }
        __syncthreads();
    }
    float tsum = 0.0f;
    #pragma unroll
    for (int pp = 0; pp < 4; pp++) {
        const int n = tile_n + ty * 4 + pp;
        float4 v = {acc[pp][0], acc[pp][1], acc[pp][2], acc[pp][3]};
        tsum += v.x + v.y + v.z + v.w;
        *(float4*)&Eo[(size_t)n * HWN + tile_m + tx * 4] = v;
    }
    tsum = waveReduceSum(tsum);
    const int lane = t & 63, wid = t >> 6;
    if (lane == 0) red[wid] = tsum;
    __syncthreads();
    if (t == 0) atomicAdd(&means[i * 2 + j], red[0] + red[1] + red[2] + red[3]);
}

// ---------- in-place row softmax over m (row length 1024, one block per row)
__global__ __launch_bounds__(256) void softmax_kernel(float* __restrict__ E) {
    float* rowp = E + (size_t)blockIdx.x * HWN;
    const int t = threadIdx.x;
    float4 v = ((const float4*)rowp)[t];
    float mx = fmaxf(fmaxf(v.x, v.y), fmaxf(v.z, v.w));
    mx = waveReduceMax(mx);
    __shared__ float redm[4], reds[4];
    const int lane = t & 63, wid = t >> 6;
    if (lane == 0) redm[wid] = mx;
    __syncthreads();
    mx = fmaxf(fmaxf(redm[0], redm[1]), fmaxf(redm[2], redm[3]));
    const float e0 = __expf(v.x - mx), e1 = __expf(v.y - mx);
    const float e2 = __expf(v.z - mx), e3 = __expf(v.w - mx);
    float s = waveReduceSum(e0 + e1 + e2 + e3);
    if (lane == 0) reds[wid] = s;
    __syncthreads();
    const float inv = 1.0f / (reds[0] + reds[1] + reds[2] + reds[3]);
    float4 o = {e0 * inv, e1 * inv, e2 * inv, e3 * inv};
    ((float4*)rowp)[t] = o;
}

// ---------- out[c][n] (+)= sum_m V[c][m] * P[n][m]   (contraction over contiguous m)
// grid: x = n-tiles (16), y = c-tiles (8), z = i*Bc + bb
__global__ __launch_bounds__(256) void gemmOut_kernel(
    const float* __restrict__ Vp, const float* __restrict__ P,
    float* __restrict__ outp, int b0, int Bc, int accumulate)
{
    __shared__ __align__(16) float vs[BK][LDP];  // [m-k][c]
    __shared__ __align__(16) float ps[BK][LDP];  // [m-k][n]
    const int z = blockIdx.z;
    const int i = z / Bc, bb = z % Bc, b = b0 + bb;
    const float* V  = Vp + (size_t)(i * BATCH + b) * CCH * HWN;
    const float* Pm = P  + (size_t)(i * Bc + bb) * HWN * HWN;
    float* O = outp + (size_t)(i * BATCH + b) * CCH * HWN;
    const int tile_n = blockIdx.x * 64;
    const int tile_c = blockIdx.y * 64;
    const int t = threadIdx.x;
    const int tx = t & 15, ty = t >> 4;
    const int row = t >> 2, kp = (t & 3) * 4;

    float acc[4][4] = {};
    for (int m0 = 0; m0 < HWN; m0 += BK) {
        const float4 vv = *(const float4*)&V [(size_t)(tile_c + row) * HWN + m0 + kp];
        const float4 pv = *(const float4*)&Pm[(size_t)(tile_n + row) * HWN + m0 + kp];
        vs[kp + 0][row] = vv.x; vs[kp + 1][row] = vv.y; vs[kp + 2][row] = vv.z; vs[kp + 3][row] = vv.w;
        ps[kp + 0][row] = pv.x; ps[kp + 1][row] = pv.y; ps[kp + 2][row] = pv.z; ps[kp + 3][row] = pv.w;
        __syncthreads();
        #pragma unroll
        for (int k = 0; k < BK; k++) {
            const float4 av  = *(const float4*)&vs[k][ty * 4];
            const float4 bv4 = *(const float4*)&ps[k][tx * 4];
            const float ar[4] = {av.x, av.y, av.z, av.w};
            const float br[4] = {bv4.x, bv4.y, bv4.z, bv4.w};
            #pragma unroll
            for (int pp = 0; pp < 4; pp++)
                #pragma unroll
                for (int qq = 0; qq < 4; qq++)
                    acc[pp][qq] = fmaf(ar[pp], br[qq], acc[pp][qq]);
        }
        __syncthreads();
    }
    #pragma unroll
    for (int pp = 0; pp < 4; pp++) {
        const int c = tile_c + ty * 4 + pp;
        float* dst = &O[(size_t)c * HWN + tile_n + tx * 4];
        float4 v = {acc[pp][0], acc[pp][1], acc[pp][2], acc[pp][3]};
        if (accumulate) {
            const float4 old = *(const float4*)dst;
            v.x += old.x; v.y += old.y; v.z += old.z; v.w += old.w;
        }
        *(float4*)dst = v;
    }
}

// ---------- alphas = row-softmax over j of means/(B*HW*HW), written after out
__global__ void alphas_kernel(const float* __restrict__ means, float* __restrict__ outp) {
    if (threadIdx.x != 0) return;
    const float cnt = (float)BATCH * (float)HWN * (float)HWN;
    float m[4];
    #pragma unroll
    for (int k = 0; k < 4; k++) m[k] = means[k] / cnt;
    #pragma unroll
    for (int i = 0; i < 2; i++) {
        const float a = m[i * 2 + 0], bsc = m[i * 2 + 1];
        const float mx = fmaxf(a, bsc);
        const float ea = __expf(a - mx), eb = __expf(bsc - mx);
        const float inv = 1.0f / (ea + eb);
        outp[i * 2 + 0] = ea * inv;
        outp[i * 2 + 1] = eb * inv;
    }
}

extern "C" void kernel_launch(void* const* d_in, const int* in_sizes, int n_in,
                              void* d_out, int out_size, void* d_ws, size_t ws_size,
                              hipStream_t stream) {
    const float* fsrc = (const float*)d_in[0];
    const float* ftgt = (const float*)d_in[1];
    const float* Wq = (const float*)d_in[2];
    const float* bq = (const float*)d_in[3];
    const float* Wk = (const float*)d_in[4];
    const float* bk = (const float*)d_in[5];
    const float* Wv = (const float*)d_in[6];
    const float* bv = (const float*)d_in[7];
    float* outp = (float*)d_out;

    const size_t PROJ = (size_t)NUMH * BATCH * CCH * HWN;  // 8,388,608 floats
    float* ws = (float*)d_ws;
    float* Qt = ws;                // (i,b): [c_out][n] — Q transposed, contraction-major
    float* Kp = Qt + PROJ;         // (j,b): [c_out][m]
    float* Vp = Kp + PROJ;         // (i,b): [c_out][m]
    float* means = Vp + PROJ;      // 4 accumulators (+pad to 16)
    float* Ebuf = means + 16;      // chunked energy / attention buffer

    // pick largest batch-chunk Bc whose E buffer fits the remaining workspace
    const size_t used = 3 * PROJ + 16;
    const size_t ws_floats = ws_size / sizeof(float);
    const size_t avail = ws_floats > used ? ws_floats - used : 0;
    int Bc = 8;
    while (Bc > 1 && (size_t)NUMH * Bc * HWN * HWN > avail) Bc >>= 1;

    zero_means_kernel<<<1, 64, 0, stream>>>(means);
    proj_kernel<<<dim3(16, 8, 48), 256, 0, stream>>>(fsrc, ftgt, Wq, bq, Wk, bk, Wv, bv, Qt, Kp, Vp);

    const int nch = BATCH / Bc;
    for (int j = 0; j < NUMH; j++) {
        for (int ch = 0; ch < nch; ch++) {
            const int b0 = ch * Bc;
            gemmE_kernel<<<dim3(16, 16, NUMH * Bc), 256, 0, stream>>>(Qt, Kp, Ebuf, means, j, b0, Bc);
            softmax_kernel<<<NUMH * Bc * HWN, 256, 0, stream>>>(Ebuf);
            gemmOut_kernel<<<dim3(16, 8, NUMH * Bc), 256, 0, stream>>>(Vp, Ebuf, outp, b0, Bc, j);
        }
    }
    alphas_kernel<<<1, 1, 0, stream>>>(means, outp + (out_size - 4));
}

// Round 2
// 376.081 us; speedup vs baseline: 3.5178x; 3.5178x over previous
//
#include <hip/hip_runtime.h>

#define NUMH 2
#define BATCH 8
#define CCH 512
#define HWN 1024

typedef unsigned short u16;
typedef unsigned int u32;
typedef __attribute__((ext_vector_type(8))) short bf16x8;
typedef __attribute__((ext_vector_type(4))) float f32x4;

__device__ __forceinline__ u16 f2bf(float x) {
    u32 u = __float_as_uint(x);
    return (u16)((u + 0x7fffu + ((u >> 16) & 1u)) >> 16);
}
__device__ __forceinline__ float bf2f(u16 h) { return __uint_as_float(((u32)h) << 16); }

__device__ __forceinline__ float waveReduceSum(float v) {
#pragma unroll
    for (int off = 32; off > 0; off >>= 1) v += __shfl_xor(v, off);
    return v;
}
__device__ __forceinline__ float waveReduceMax(float v) {
#pragma unroll
    for (int off = 32; off > 0; off >>= 1) v = fmaxf(v, __shfl_xor(v, off));
    return v;
}

__global__ void zero_means_kernel(float* means) {
    if (threadIdx.x < 4) means[threadIdx.x] = 0.0f;
}

// ---- stage a [128 rows][32 k] bf16 tile into an 8 KiB LDS array via global_load_lds.
// 16B-chunk XOR swizzle: physical slot p holds logical (n=p>>2, k4=(p&3)^((n>>1)&3)).
__device__ __forceinline__ void stage_tile(const u16* __restrict__ src, int ld, int k0,
                                           u16* lds_arr, int w, int l) {
#pragma unroll
    for (int inst = 0; inst < 2; inst++) {
        const int p = w * 128 + inst * 64 + l;
        const int n = p >> 2;
        const int k4 = (p & 3) ^ ((n >> 1) & 3);
        const u16* g = src + n * ld + k0 + k4 * 8;
        u16* lp = lds_arr + (w * 128 + inst * 64) * 8;  // wave-uniform; lane adds l*16B
        __builtin_amdgcn_global_load_lds(
            (const __attribute__((address_space(1))) u32*)g,
            (__attribute__((address_space(3))) u32*)lp, 16, 0, 0);
    }
}

__device__ __forceinline__ bf16x8 frag_ld(const u16* lds_arr, int row, int kq) {
    const int slot = row * 4 + (kq ^ ((row >> 1) & 3));
    return *(const bf16x8*)(lds_arr + slot * 8);
}

// ---- shared MFMA core: D[128][128] tile, A=[rows][K] bf16, B=[cols][K] bf16,
// D[r][c] = sum_k A[r][k]*B[c][k].  SPLIT: A=Ah+Al, B=Bh+Bl, 3-product compensation.
template<bool SPLIT>
__device__ __forceinline__ void mm_core(const u16* __restrict__ Ah, const u16* __restrict__ Al,
                                        const u16* __restrict__ Bh, const u16* __restrict__ Bl,
                                        int K, int ldA, int ldB,
                                        u16* sAh, u16* sAl, u16* sBh, u16* sBl,
                                        f32x4 acc[4][4]) {
    const int t = threadIdx.x, w = t >> 6, l = t & 63;
    const int wr = w >> 1, wc = w & 1;
    const int fr = l & 15, kq = l >> 4;
    for (int k0 = 0; k0 < K; k0 += 32) {
        __syncthreads();
        stage_tile(Ah, ldA, k0, sAh, w, l);
        stage_tile(Bh, ldB, k0, sBh, w, l);
        if (SPLIT) {
            stage_tile(Al, ldA, k0, sAl, w, l);
            stage_tile(Bl, ldB, k0, sBl, w, l);
        }
        __syncthreads();
        bf16x8 ah[4], bh[4], al[4], bl[4];
#pragma unroll
        for (int mi = 0; mi < 4; mi++) {
            const int row = wr * 64 + mi * 16 + fr;
            ah[mi] = frag_ld(sAh, row, kq);
            if (SPLIT) al[mi] = frag_ld(sAl, row, kq);
        }
#pragma unroll
        for (int ni = 0; ni < 4; ni++) {
            const int col = wc * 64 + ni * 16 + fr;
            bh[ni] = frag_ld(sBh, col, kq);
            if (SPLIT) bl[ni] = frag_ld(sBl, col, kq);
        }
#pragma unroll
        for (int mi = 0; mi < 4; mi++)
#pragma unroll
            for (int ni = 0; ni < 4; ni++) {
                acc[mi][ni] = __builtin_amdgcn_mfma_f32_16x16x32_bf16(ah[mi], bh[ni], acc[mi][ni], 0, 0, 0);
                if (SPLIT) {
                    acc[mi][ni] = __builtin_amdgcn_mfma_f32_16x16x32_bf16(ah[mi], bl[ni], acc[mi][ni], 0, 0, 0);
                    acc[mi][ni] = __builtin_amdgcn_mfma_f32_16x16x32_bf16(al[mi], bh[ni], acc[mi][ni], 0, 0, 0);
                }
            }
    }
}

#define ACC_INIT(acc)                                         \
    f32x4 acc[4][4];                                          \
    _Pragma("unroll") for (int mi_ = 0; mi_ < 4; mi_++)       \
    _Pragma("unroll") for (int ni_ = 0; ni_ < 4; ni_++)       \
        acc[mi_][ni_] = (f32x4){0.f, 0.f, 0.f, 0.f};

// ---- transpose+split: X fp32 [ib][C][HW]  ->  Xt hi/lo bf16 [ib][HW][C]
__global__ __launch_bounds__(256) void tsplit_kernel(
    const float* __restrict__ tgt, const float* __restrict__ src,
    u16* __restrict__ Tth, u16* __restrict__ Ttl,
    u16* __restrict__ Sth, u16* __restrict__ Stl) {
    __shared__ float s[64][65];
    const int z = blockIdx.z;
    const int ib = z & 15;
    const float* X = (z >> 4 ? src : tgt) + (size_t)ib * CCH * HWN;
    u16* Oh = (z >> 4 ? Sth : Tth) + (size_t)ib * HWN * CCH;
    u16* Ol = (z >> 4 ? Stl : Ttl) + (size_t)ib * HWN * CCH;
    const int n0 = blockIdx.x * 64, c0 = blockIdx.y * 64;
    const int t = threadIdx.x;
    {
        const int cc = t >> 4, nch = (t & 15) * 4;
#pragma unroll
        for (int r = 0; r < 4; r++) {
            const float4 v = *(const float4*)&X[(size_t)(c0 + cc + r * 16) * HWN + n0 + nch];
            s[cc + r * 16][nch + 0] = v.x;
            s[cc + r * 16][nch + 1] = v.y;
            s[cc + r * 16][nch + 2] = v.z;
            s[cc + r * 16][nch + 3] = v.w;
        }
    }
    __syncthreads();
    const int nl = t & 63, g = t >> 6;
    __attribute__((aligned(16))) u16 hibuf[16];
    __attribute__((aligned(16))) u16 lobuf[16];
#pragma unroll
    for (int cc = 0; cc < 16; cc++) {
        const float v = s[g * 16 + cc][nl];
        const u16 hi = f2bf(v);
        hibuf[cc] = hi;
        lobuf[cc] = f2bf(v - bf2f(hi));
    }
    const size_t orow = (size_t)(n0 + nl) * CCH + c0 + g * 16;
#pragma unroll
    for (int q = 0; q < 2; q++) {
        *(uint4*)&Oh[orow + q * 8] = *(const uint4*)&hibuf[q * 8];
        *(uint4*)&Ol[orow + q * 8] = *(const uint4*)&lobuf[q * 8];
    }
}

// ---- weights fp32 -> bf16 hi/lo (Wq, Wk) and hi (Wv)
__global__ __launch_bounds__(256) void convw_kernel(
    const float* __restrict__ Wq, const float* __restrict__ Wk, const float* __restrict__ Wv,
    u16* __restrict__ Wqh, u16* __restrict__ Wql,
    u16* __restrict__ Wkh, u16* __restrict__ Wkl, u16* __restrict__ Wvh) {
    const int idx = (blockIdx.x * 256 + threadIdx.x) * 4;  // over NUMH*C*C = 524288
    {
        const float4 v = *(const float4*)&Wq[idx];
        u16 h0 = f2bf(v.x), h1 = f2bf(v.y), h2 = f2bf(v.z), h3 = f2bf(v.w);
        uint2 h = {(u32)h0 | ((u32)h1 << 16), (u32)h2 | ((u32)h3 << 16)};
        uint2 lo = {(u32)f2bf(v.x - bf2f(h0)) | ((u32)f2bf(v.y - bf2f(h1)) << 16),
                    (u32)f2bf(v.z - bf2f(h2)) | ((u32)f2bf(v.w - bf2f(h3)) << 16)};
        *(uint2*)&Wqh[idx] = h;
        *(uint2*)&Wql[idx] = lo;
    }
    {
        const float4 v = *(const float4*)&Wk[idx];
        u16 h0 = f2bf(v.x), h1 = f2bf(v.y), h2 = f2bf(v.z), h3 = f2bf(v.w);
        uint2 h = {(u32)h0 | ((u32)h1 << 16), (u32)h2 | ((u32)h3 << 16)};
        uint2 lo = {(u32)f2bf(v.x - bf2f(h0)) | ((u32)f2bf(v.y - bf2f(h1)) << 16),
                    (u32)f2bf(v.z - bf2f(h2)) | ((u32)f2bf(v.w - bf2f(h3)) << 16)};
        *(uint2*)&Wkh[idx] = h;
        *(uint2*)&Wkl[idx] = lo;
    }
    {
        const float4 v = *(const float4*)&Wv[idx];
        uint2 h = {(u32)f2bf(v.x) | ((u32)f2bf(v.y) << 16),
                   (u32)f2bf(v.z) | ((u32)f2bf(v.w) << 16)};
        *(uint2*)&Wvh[idx] = h;
    }
}

// ---- Q/K projection: D[n][o] = sum_c Xt[n][c]*W[o][c] + bias[o], split in/out
__global__ __launch_bounds__(256) void proj_qk_kernel(
    const u16* __restrict__ Tth, const u16* __restrict__ Ttl,
    const u16* __restrict__ Sth, const u16* __restrict__ Stl,
    const u16* __restrict__ Wqh, const u16* __restrict__ Wql,
    const u16* __restrict__ Wkh, const u16* __restrict__ Wkl,
    const float* __restrict__ bq, const float* __restrict__ bk,
    u16* __restrict__ Qh, u16* __restrict__ Ql,
    u16* __restrict__ Kh, u16* __restrict__ Kl) {
    __shared__ __align__(16) u16 lds[4][4096];
    const int z = blockIdx.z;
    const int b = z & 7, i = (z >> 3) & 1, p = z >> 4;
    const size_t ib = (size_t)(i * BATCH + b) * HWN * CCH;
    const u16* Asrc_h = (p ? Sth : Tth) + ib;
    const u16* Asrc_l = (p ? Stl : Ttl) + ib;
    const u16* Bsrc_h = (p ? Wkh : Wqh) + (size_t)i * CCH * CCH;
    const u16* Bsrc_l = (p ? Wkl : Wql) + (size_t)i * CCH * CCH;
    const float* bias = (p ? bk : bq) + i * CCH;
    u16* Oh = (p ? Kh : Qh) + ib;
    u16* Ol = (p ? Kl : Ql) + ib;
    const int tile_m = blockIdx.y * 128, tile_n = blockIdx.x * 128;

    ACC_INIT(acc)
    mm_core<true>(Asrc_h + (size_t)tile_m * CCH, Asrc_l + (size_t)tile_m * CCH,
                  Bsrc_h + (size_t)tile_n * CCH, Bsrc_l + (size_t)tile_n * CCH,
                  CCH, CCH, CCH, lds[0], lds[1], lds[2], lds[3], acc);

    const int t = threadIdx.x, w = t >> 6, l = t & 63;
    const int wr = w >> 1, wc = w & 1, fr = l & 15, fq = l >> 4;
#pragma unroll
    for (int ni = 0; ni < 4; ni++) {
        const int col = tile_n + wc * 64 + ni * 16 + fr;
        const float bb = bias[col];
#pragma unroll
        for (int mi = 0; mi < 4; mi++)
#pragma unroll
            for (int r = 0; r < 4; r++) {
                const int row = tile_m + wr * 64 + mi * 16 + fq * 4 + r;
                const float v = acc[mi][ni][r] + bb;
                const u16 hi = f2bf(v);
                Oh[(size_t)row * CCH + col] = hi;
                Ol[(size_t)row * CCH + col] = f2bf(v - bf2f(hi));
            }
    }
}

// ---- V projection: D[c][n] = sum_cin Wv[c][cin]*Xt[n][cin] + bv[c], bf16 out
__global__ __launch_bounds__(256) void proj_v_kernel(
    const u16* __restrict__ Wvh, const u16* __restrict__ Tth,
    const float* __restrict__ bvv, u16* __restrict__ Vb) {
    __shared__ __align__(16) u16 lds[2][4096];
    const int z = blockIdx.z;
    const int b = z & 7, i = z >> 3;
    const size_t ib = (size_t)(i * BATCH + b) * HWN * CCH;
    const u16* A = Wvh + (size_t)i * CCH * CCH;
    const u16* B = Tth + ib;
    const int tile_m = blockIdx.y * 128, tile_n = blockIdx.x * 128;

    ACC_INIT(acc)
    mm_core<false>(A + (size_t)tile_m * CCH, nullptr,
                   B + (size_t)tile_n * CCH, nullptr,
                   CCH, CCH, CCH, lds[0], nullptr, lds[1], nullptr, acc);

    u16* Ov = Vb + (size_t)(i * BATCH + b) * CCH * HWN;
    const int t = threadIdx.x, w = t >> 6, l = t & 63;
    const int wr = w >> 1, wc = w & 1, fr = l & 15, fq = l >> 4;
#pragma unroll
    for (int mi = 0; mi < 4; mi++)
#pragma unroll
        for (int r = 0; r < 4; r++) {
            const int row = tile_m + wr * 64 + mi * 16 + fq * 4 + r;
            const float bb = bvv[i * CCH + row];
#pragma unroll
            for (int ni = 0; ni < 4; ni++) {
                const int col = tile_n + wc * 64 + ni * 16 + fr;
                Ov[(size_t)row * HWN + col] = f2bf(acc[mi][ni][r] + bb);
            }
        }
}

// ---- energy: E[n][m] = sum_c Q[n][c]*K[m][c] (split), fp32 out + tile-sum -> means
__global__ __launch_bounds__(256) void gemmE_kernel(
    const u16* __restrict__ Qh, const u16* __restrict__ Ql,
    const u16* __restrict__ Kh, const u16* __restrict__ Kl,
    float* __restrict__ E, float* __restrict__ means, int j, int b0, int Bc) {
    __shared__ __align__(16) u16 lds[4][4096];
    __shared__ float redsum[4];
    const int z = blockIdx.z;
    const int i = z / Bc, bb = z % Bc, b = b0 + bb;
    const size_t offA = (size_t)(i * BATCH + b) * HWN * CCH;
    const size_t offB = (size_t)(j * BATCH + b) * HWN * CCH;
    float* Eo = E + (size_t)(i * Bc + bb) * HWN * HWN;
    const int tile_m = blockIdx.y * 128, tile_n = blockIdx.x * 128;

    ACC_INIT(acc)
    mm_core<true>(Qh + offA + (size_t)tile_m * CCH, Ql + offA + (size_t)tile_m * CCH,
                  Kh + offB + (size_t)tile_n * CCH, Kl + offB + (size_t)tile_n * CCH,
                  CCH, CCH, CCH, lds[0], lds[1], lds[2], lds[3], acc);

    const int t = threadIdx.x, w = t >> 6, l = t & 63;
    const int wr = w >> 1, wc = w & 1, fr = l & 15, fq = l >> 4;
    float tsum = 0.0f;
#pragma unroll
    for (int mi = 0; mi < 4; mi++)
#pragma unroll
        for (int r = 0; r < 4; r++) {
            const int row = tile_m + wr * 64 + mi * 16 + fq * 4 + r;
#pragma unroll
            for (int ni = 0; ni < 4; ni++) {
                const int col = tile_n + wc * 64 + ni * 16 + fr;
                const float v = acc[mi][ni][r];
                Eo[(size_t)row * HWN + col] = v;
                tsum += v;
            }
        }
    tsum = waveReduceSum(tsum);
    if (l == 0) redsum[w] = tsum;
    __syncthreads();
    if (t == 0) atomicAdd(&means[i * 2 + j], redsum[0] + redsum[1] + redsum[2] + redsum[3]);
}

// ---- row softmax: E fp32 row -> P bf16 row
__global__ __launch_bounds__(256) void softmax_kernel(const float* __restrict__ E,
                                                      u16* __restrict__ P) {
    const float* rowp = E + (size_t)blockIdx.x * HWN;
    u16* pout = P + (size_t)blockIdx.x * HWN;
    const int t = threadIdx.x;
    const float4 v = ((const float4*)rowp)[t];
    float mx = fmaxf(fmaxf(v.x, v.y), fmaxf(v.z, v.w));
    mx = waveReduceMax(mx);
    __shared__ float redm[4], reds[4];
    const int lane = t & 63, wid = t >> 6;
    if (lane == 0) redm[wid] = mx;
    __syncthreads();
    mx = fmaxf(fmaxf(redm[0], redm[1]), fmaxf(redm[2], redm[3]));
    const float e0 = __expf(v.x - mx), e1 = __expf(v.y - mx);
    const float e2 = __expf(v.z - mx), e3 = __expf(v.w - mx);
    float s = waveReduceSum(e0 + e1 + e2 + e3);
    if (lane == 0) reds[wid] = s;
    __syncthreads();
    const float inv = 1.0f / (reds[0] + reds[1] + reds[2] + reds[3]);
    uint2 pk;
    pk.x = (u32)f2bf(e0 * inv) | ((u32)f2bf(e1 * inv) << 16);
    pk.y = (u32)f2bf(e2 * inv) | ((u32)f2bf(e3 * inv) << 16);
    *(uint2*)&pout[t * 4] = pk;
}

// ---- out[c][n] (+)= sum_m V[c][m]*P[n][m], plain bf16 MFMA, fp32 out
__global__ __launch_bounds__(256) void gemmOut_kernel(
    const u16* __restrict__ Vb, const u16* __restrict__ P,
    float* __restrict__ outp, int b0, int Bc, int accumulate) {
    __shared__ __align__(16) u16 lds[2][4096];
    const int z = blockIdx.z;
    const int i = z / Bc, bb = z % Bc, b = b0 + bb;
    const u16* A = Vb + (size_t)(i * BATCH + b) * CCH * HWN;
    const u16* Bp = P + (size_t)(i * Bc + bb) * HWN * HWN;
    float* O = outp + (size_t)(i * BATCH + b) * CCH * HWN;
    const int tile_m = blockIdx.y * 128, tile_n = blockIdx.x * 128;

    ACC_INIT(acc)
    mm_core<false>(A + (size_t)tile_m * HWN, nullptr,
                   Bp + (size_t)tile_n * HWN, nullptr,
                   HWN, HWN, HWN, lds[0], nullptr, lds[1], nullptr, acc);

    const int t = threadIdx.x, w = t >> 6, l = t & 63;
    const int wr = w >> 1, wc = w & 1, fr = l & 15, fq = l >> 4;
#pragma unroll
    for (int mi = 0; mi < 4; mi++)
#pragma unroll
        for (int r = 0; r < 4; r++) {
            const int row = tile_m + wr * 64 + mi * 16 + fq * 4 + r;
#pragma unroll
            for (int ni = 0; ni < 4; ni++) {
                const int col = tile_n + wc * 64 + ni * 16 + fr;
                float* dst = &O[(size_t)row * HWN + col];
                float v = acc[mi][ni][r];
                if (accumulate) v += *dst;
                *dst = v;
            }
        }
}

__global__ void alphas_kernel(const float* __restrict__ means, float* __restrict__ outp) {
    if (threadIdx.x != 0) return;
    const float cnt = (float)BATCH * (float)HWN * (float)HWN;
    float m[4];
#pragma unroll
    for (int k = 0; k < 4; k++) m[k] = means[k] / cnt;
#pragma unroll
    for (int i = 0; i < 2; i++) {
        const float a = m[i * 2 + 0], bsc = m[i * 2 + 1];
        const float mx = fmaxf(a, bsc);
        const float ea = __expf(a - mx), eb = __expf(bsc - mx);
        const float inv = 1.0f / (ea + eb);
        outp[i * 2 + 0] = ea * inv;
        outp[i * 2 + 1] = eb * inv;
    }
}

extern "C" void kernel_launch(void* const* d_in, const int* in_sizes, int n_in,
                              void* d_out, int out_size, void* d_ws, size_t ws_size,
                              hipStream_t stream) {
    const float* fsrc = (const float*)d_in[0];
    const float* ftgt = (const float*)d_in[1];
    const float* Wq = (const float*)d_in[2];
    const float* bq = (const float*)d_in[3];
    const float* Wk = (const float*)d_in[4];
    const float* bk = (const float*)d_in[5];
    const float* Wv = (const float*)d_in[6];
    const float* bv = (const float*)d_in[7];
    float* outp = (float*)d_out;

    const size_t SZ_ACT = (size_t)NUMH * BATCH * HWN * CCH * 2;  // 16 MiB bf16
    const size_t SZ_W = (size_t)NUMH * CCH * CCH * 2;            // 1 MiB bf16
    char* w = (char*)d_ws;
    u16* Qh = (u16*)w; w += SZ_ACT;
    u16* Ql = (u16*)w; w += SZ_ACT;
    u16* Kh = (u16*)w; w += SZ_ACT;
    u16* Kl = (u16*)w; w += SZ_ACT;
    u16* Vb = (u16*)w; w += SZ_ACT;
    u16* Wqh = (u16*)w; w += SZ_W;
    u16* Wql = (u16*)w; w += SZ_W;
    u16* Wkh = (u16*)w; w += SZ_W;
    u16* Wkl = (u16*)w; w += SZ_W;
    u16* Wvh = (u16*)w; w += SZ_W;
    float* means = (float*)w; w += 64;
    char* region = w;  // transpose buffers live here early; E/P overlay later
    u16* Tth = (u16*)region;
    u16* Ttl = (u16*)(region + SZ_ACT);
    u16* Sth = (u16*)(region + 2 * SZ_ACT);
    u16* Stl = (u16*)(region + 3 * SZ_ACT);

    const size_t base_used = (size_t)(region - (char*)d_ws);
    int Bc = 8;
    while (Bc > 1) {
        size_t need = (size_t)NUMH * Bc * HWN * HWN * 6;  // 4B E + 2B P per element
        size_t tneed = need > 4 * SZ_ACT ? need : 4 * SZ_ACT;
        if (base_used + tneed <= ws_size) break;
        Bc >>= 1;
    }
    float* E = (float*)region;
    u16* P = (u16*)(region + (size_t)NUMH * Bc * HWN * HWN * 4);

    zero_means_kernel<<<1, 64, 0, stream>>>(means);
    convw_kernel<<<512, 256, 0, stream>>>(Wq, Wk, Wv, Wqh, Wql, Wkh, Wkl, Wvh);
    tsplit_kernel<<<dim3(16, 8, 32), 256, 0, stream>>>(ftgt, fsrc, Tth, Ttl, Sth, Stl);
    proj_qk_kernel<<<dim3(4, 8, 32), 256, 0, stream>>>(Tth, Ttl, Sth, Stl,
                                                       Wqh, Wql, Wkh, Wkl, bq, bk,
                                                       Qh, Ql, Kh, Kl);
    proj_v_kernel<<<dim3(8, 4, 16), 256, 0, stream>>>(Wvh, Tth, bv, Vb);

    const int nch = BATCH / Bc;
    for (int j = 0; j < NUMH; j++) {
        for (int ch = 0; ch < nch; ch++) {
            const int b0 = ch * Bc;
            gemmE_kernel<<<dim3(8, 8, NUMH * Bc), 256, 0, stream>>>(Qh, Ql, Kh, Kl, E, means, j, b0, Bc);
            softmax_kernel<<<NUMH * Bc * HWN, 256, 0, stream>>>(E, P);
            gemmOut_kernel<<<dim3(8, 4, NUMH * Bc), 256, 0, stream>>>(Vb, P, outp, b0, Bc, j);
        }
    }
    alphas_kernel<<<1, 1, 0, stream>>>(means, outp + (out_size - 4));
}

// Round 3
// 360.845 us; speedup vs baseline: 3.6664x; 1.0422x over previous
//
#include <hip/hip_runtime.h>

#define NUMH 2
#define BATCH 8
#define CCH 512
#define HWN 1024

typedef unsigned short u16;
typedef unsigned int u32;
typedef __attribute__((ext_vector_type(8))) short bf16x8;
typedef __attribute__((ext_vector_type(4))) float f32x4;

__device__ __forceinline__ u16 f2bf(float x) {
    u32 u = __float_as_uint(x);
    return (u16)((u + 0x7fffu + ((u >> 16) & 1u)) >> 16);
}
__device__ __forceinline__ float bf2f(u16 h) { return __uint_as_float(((u32)h) << 16); }

__device__ __forceinline__ float waveReduceSum(float v) {
#pragma unroll
    for (int off = 32; off > 0; off >>= 1) v += __shfl_xor(v, off);
    return v;
}
__device__ __forceinline__ float waveReduceMax(float v) {
#pragma unroll
    for (int off = 32; off > 0; off >>= 1) v = fmaxf(v, __shfl_xor(v, off));
    return v;
}

__global__ void zero_means_kernel(float* means) {
    if (threadIdx.x < 4) means[threadIdx.x] = 0.0f;
}

// ---- stage a [128 rows][32 k] bf16 tile into an 8 KiB LDS array via global_load_lds.
// 16B-chunk XOR swizzle: physical slot p holds logical (n=p>>2, k4=(p&3)^((n>>1)&3)).
__device__ __forceinline__ void stage_tile(const u16* __restrict__ src, int ld, int k0,
                                           u16* lds_arr, int w, int l) {
#pragma unroll
    for (int inst = 0; inst < 2; inst++) {
        const int p = w * 128 + inst * 64 + l;
        const int n = p >> 2;
        const int k4 = (p & 3) ^ ((n >> 1) & 3);
        const u16* g = src + n * ld + k0 + k4 * 8;
        u16* lp = lds_arr + (w * 128 + inst * 64) * 8;  // wave-uniform; lane adds l*16B
        __builtin_amdgcn_global_load_lds(
            (const __attribute__((address_space(1))) u32*)g,
            (__attribute__((address_space(3))) u32*)lp, 16, 0, 0);
    }
}

__device__ __forceinline__ bf16x8 frag_ld(const u16* lds_arr, int row, int kq) {
    const int slot = row * 4 + (kq ^ ((row >> 1) & 3));
    return *(const bf16x8*)(lds_arr + slot * 8);
}

// ---- shared MFMA core: D[128][128] tile, A=[rows][K] bf16, B=[cols][K] bf16,
// D[r][c] = sum_k A[r][k]*B[c][k].  SPLIT: A=Ah+Al, B=Bh+Bl, 3-product compensation.
template<bool SPLIT>
__device__ __forceinline__ void mm_core(const u16* __restrict__ Ah, const u16* __restrict__ Al,
                                        const u16* __restrict__ Bh, const u16* __restrict__ Bl,
                                        int K, int ldA, int ldB,
                                        u16* sAh, u16* sAl, u16* sBh, u16* sBl,
                                        f32x4 acc[4][4]) {
    const int t = threadIdx.x, w = t >> 6, l = t & 63;
    const int wr = w >> 1, wc = w & 1;
    const int fr = l & 15, kq = l >> 4;
    for (int k0 = 0; k0 < K; k0 += 32) {
        __syncthreads();
        stage_tile(Ah, ldA, k0, sAh, w, l);
        stage_tile(Bh, ldB, k0, sBh, w, l);
        if (SPLIT) {
            stage_tile(Al, ldA, k0, sAl, w, l);
            stage_tile(Bl, ldB, k0, sBl, w, l);
        }
        __syncthreads();
        bf16x8 ah[4], bh[4], al[4], bl[4];
#pragma unroll
        for (int mi = 0; mi < 4; mi++) {
            const int row = wr * 64 + mi * 16 + fr;
            ah[mi] = frag_ld(sAh, row, kq);
            if (SPLIT) al[mi] = frag_ld(sAl, row, kq);
        }
#pragma unroll
        for (int ni = 0; ni < 4; ni++) {
            const int col = wc * 64 + ni * 16 + fr;
            bh[ni] = frag_ld(sBh, col, kq);
            if (SPLIT) bl[ni] = frag_ld(sBl, col, kq);
        }
#pragma unroll
        for (int mi = 0; mi < 4; mi++)
#pragma unroll
            for (int ni = 0; ni < 4; ni++) {
                acc[mi][ni] = __builtin_amdgcn_mfma_f32_16x16x32_bf16(ah[mi], bh[ni], acc[mi][ni], 0, 0, 0);
                if (SPLIT) {
                    acc[mi][ni] = __builtin_amdgcn_mfma_f32_16x16x32_bf16(ah[mi], bl[ni], acc[mi][ni], 0, 0, 0);
                    acc[mi][ni] = __builtin_amdgcn_mfma_f32_16x16x32_bf16(al[mi], bh[ni], acc[mi][ni], 0, 0, 0);
                }
            }
    }
}

#define ACC_INIT(acc)                                         \
    f32x4 acc[4][4];                                          \
    _Pragma("unroll") for (int mi_ = 0; mi_ < 4; mi_++)       \
    _Pragma("unroll") for (int ni_ = 0; ni_ < 4; ni_++)       \
        acc[mi_][ni_] = (f32x4){0.f, 0.f, 0.f, 0.f};

#define SMEM_BYTES 33792

// ---- epilogue: 128x128 bf16 tile (hi, optional lo) via LDS assembly -> coalesced stores
// O points at tile origin.  biasCol indexed by local col, biasRow by local row (either null).
template<bool HAS_LO, bool BCOL, bool BROW>
__device__ __forceinline__ void epi_bf16(char* smem, const f32x4 acc[4][4],
                                         const float* biasCol, const float* biasRow,
                                         u16* Oh, u16* Ol, int ldO) {
    const int t = threadIdx.x, w = t >> 6, l = t & 63;
    const int wr = w >> 1, wc = w & 1, fr = l & 15, fq = l >> 4;
    u16* sb16 = (u16*)smem;   // [128][132]
    u32* sb32 = (u32*)smem;   // [128][66]
#pragma unroll
    for (int pass = 0; pass < (HAS_LO ? 2 : 1); pass++) {
        __syncthreads();
#pragma unroll
        for (int ni = 0; ni < 4; ni++) {
            const int col = wc * 64 + ni * 16 + fr;
            const float bc = BCOL ? biasCol[col] : 0.0f;
#pragma unroll
            for (int mi = 0; mi < 4; mi++)
#pragma unroll
                for (int r = 0; r < 4; r++) {
                    const int row = wr * 64 + mi * 16 + fq * 4 + r;
                    float v = acc[mi][ni][r] + bc + (BROW ? biasRow[row] : 0.0f);
                    const u16 h = f2bf(v);
                    sb16[row * 132 + col] = pass ? f2bf(v - bf2f(h)) : h;
                }
        }
        __syncthreads();
        u16* O = pass ? Ol : Oh;
#pragma unroll
        for (int it = 0; it < 8; it++) {
            const int idx = it * 256 + t;       // 128 rows * 16 chunks of 16B
            const int rr = idx >> 4, ch = idx & 15;
            const uint4 v4 = *(const uint4*)&sb32[rr * 66 + ch * 4];
            *(uint4*)&O[(size_t)rr * ldO + ch * 8] = v4;
        }
    }
}

// ---- epilogue: 128x128 fp32 tile via LDS assembly (two row-halves) -> coalesced stores
__device__ __forceinline__ void epi_f32(char* smem, const f32x4 acc[4][4],
                                        float* O, int ldO) {
    const int t = threadIdx.x, w = t >> 6, l = t & 63;
    const int wr = w >> 1, wc = w & 1, fr = l & 15, fq = l >> 4;
    float* sf = (float*)smem;  // [64][132]
#pragma unroll
    for (int half = 0; half < 2; half++) {
        __syncthreads();
        if (wr == half) {
#pragma unroll
            for (int ni = 0; ni < 4; ni++) {
                const int col = wc * 64 + ni * 16 + fr;
#pragma unroll
                for (int mi = 0; mi < 4; mi++)
#pragma unroll
                    for (int r = 0; r < 4; r++) {
                        const int rl = mi * 16 + fq * 4 + r;
                        sf[rl * 132 + col] = acc[mi][ni][r];
                    }
            }
        }
        __syncthreads();
#pragma unroll
        for (int it = 0; it < 8; it++) {
            const int idx = it * 256 + t;       // 64 rows * 32 chunks of 16B
            const int rr = idx >> 5, ch = idx & 31;
            const float4 v4 = *(const float4*)&sf[rr * 132 + ch * 4];
            *(float4*)&O[(size_t)(half * 64 + rr) * ldO + ch * 4] = v4;
        }
    }
}

// ---- transpose+split: X fp32 [ib][C][HW]  ->  Xt hi/lo bf16 [ib][HW][C]
__global__ __launch_bounds__(256) void tsplit_kernel(
    const float* __restrict__ tgt, const float* __restrict__ src,
    u16* __restrict__ Tth, u16* __restrict__ Ttl,
    u16* __restrict__ Sth, u16* __restrict__ Stl) {
    __shared__ float s[64][65];
    const int z = blockIdx.z;
    const int ib = z & 15;
    const float* X = (z >> 4 ? src : tgt) + (size_t)ib * CCH * HWN;
    u16* Oh = (z >> 4 ? Sth : Tth) + (size_t)ib * HWN * CCH;
    u16* Ol = (z >> 4 ? Stl : Ttl) + (size_t)ib * HWN * CCH;
    const int n0 = blockIdx.x * 64, c0 = blockIdx.y * 64;
    const int t = threadIdx.x;
    {
        const int cc = t >> 4, nch = (t & 15) * 4;
#pragma unroll
        for (int r = 0; r < 4; r++) {
            const float4 v = *(const float4*)&X[(size_t)(c0 + cc + r * 16) * HWN + n0 + nch];
            s[cc + r * 16][nch + 0] = v.x;
            s[cc + r * 16][nch + 1] = v.y;
            s[cc + r * 16][nch + 2] = v.z;
            s[cc + r * 16][nch + 3] = v.w;
        }
    }
    __syncthreads();
    const int nl = t >> 2;            // local row n (0..63)
    const int cb = (t & 3) * 16;      // col chunk base
    __attribute__((aligned(16))) u16 hibuf[16];
    __attribute__((aligned(16))) u16 lobuf[16];
#pragma unroll
    for (int cc = 0; cc < 16; cc++) {
        const float v = s[cb + cc][nl];
        const u16 hi = f2bf(v);
        hibuf[cc] = hi;
        lobuf[cc] = f2bf(v - bf2f(hi));
    }
    const size_t orow = (size_t)(n0 + nl) * CCH + c0 + cb;
    *(uint4*)&Oh[orow + 0] = *(const uint4*)&hibuf[0];
    *(uint4*)&Oh[orow + 8] = *(const uint4*)&hibuf[8];
    *(uint4*)&Ol[orow + 0] = *(const uint4*)&lobuf[0];
    *(uint4*)&Ol[orow + 8] = *(const uint4*)&lobuf[8];
}

// ---- weights fp32 -> bf16 hi/lo (Wq, Wk) and hi (Wv)
__global__ __launch_bounds__(256) void convw_kernel(
    const float* __restrict__ Wq, const float* __restrict__ Wk, const float* __restrict__ Wv,
    u16* __restrict__ Wqh, u16* __restrict__ Wql,
    u16* __restrict__ Wkh, u16* __restrict__ Wkl, u16* __restrict__ Wvh) {
    const int idx = (blockIdx.x * 256 + threadIdx.x) * 4;  // over NUMH*C*C = 524288
    {
        const float4 v = *(const float4*)&Wq[idx];
        u16 h0 = f2bf(v.x), h1 = f2bf(v.y), h2 = f2bf(v.z), h3 = f2bf(v.w);
        uint2 h = {(u32)h0 | ((u32)h1 << 16), (u32)h2 | ((u32)h3 << 16)};
        uint2 lo = {(u32)f2bf(v.x - bf2f(h0)) | ((u32)f2bf(v.y - bf2f(h1)) << 16),
                    (u32)f2bf(v.z - bf2f(h2)) | ((u32)f2bf(v.w - bf2f(h3)) << 16)};
        *(uint2*)&Wqh[idx] = h;
        *(uint2*)&Wql[idx] = lo;
    }
    {
        const float4 v = *(const float4*)&Wk[idx];
        u16 h0 = f2bf(v.x), h1 = f2bf(v.y), h2 = f2bf(v.z), h3 = f2bf(v.w);
        uint2 h = {(u32)h0 | ((u32)h1 << 16), (u32)h2 | ((u32)h3 << 16)};
        uint2 lo = {(u32)f2bf(v.x - bf2f(h0)) | ((u32)f2bf(v.y - bf2f(h1)) << 16),
                    (u32)f2bf(v.z - bf2f(h2)) | ((u32)f2bf(v.w - bf2f(h3)) << 16)};
        *(uint2*)&Wkh[idx] = h;
        *(uint2*)&Wkl[idx] = lo;
    }
    {
        const float4 v = *(const float4*)&Wv[idx];
        uint2 h = {(u32)f2bf(v.x) | ((u32)f2bf(v.y) << 16),
                   (u32)f2bf(v.z) | ((u32)f2bf(v.w) << 16)};
        *(uint2*)&Wvh[idx] = h;
    }
}

// ---- Q/K projection: D[n][o] = sum_c Xt[n][c]*W[o][c] + bias[o], split in/out
__global__ __launch_bounds__(256) void proj_qk_kernel(
    const u16* __restrict__ Tth, const u16* __restrict__ Ttl,
    const u16* __restrict__ Sth, const u16* __restrict__ Stl,
    const u16* __restrict__ Wqh, const u16* __restrict__ Wql,
    const u16* __restrict__ Wkh, const u16* __restrict__ Wkl,
    const float* __restrict__ bq, const float* __restrict__ bk,
    u16* __restrict__ Qh, u16* __restrict__ Ql,
    u16* __restrict__ Kh, u16* __restrict__ Kl) {
    __shared__ __align__(16) char smem[SMEM_BYTES];
    const int z = blockIdx.z;
    const int b = z & 7, i = (z >> 3) & 1, p = z >> 4;
    const size_t ib = (size_t)(i * BATCH + b) * HWN * CCH;
    const u16* Asrc_h = (p ? Sth : Tth) + ib;
    const u16* Asrc_l = (p ? Stl : Ttl) + ib;
    const u16* Bsrc_h = (p ? Wkh : Wqh) + (size_t)i * CCH * CCH;
    const u16* Bsrc_l = (p ? Wkl : Wql) + (size_t)i * CCH * CCH;
    const float* bias = (p ? bk : bq) + i * CCH;
    u16* Oh = (p ? Kh : Qh) + ib;
    u16* Ol = (p ? Kl : Ql) + ib;
    const int tile_m = blockIdx.y * 128, tile_n = blockIdx.x * 128;

    ACC_INIT(acc)
    u16* sA = (u16*)smem;
    mm_core<true>(Asrc_h + (size_t)tile_m * CCH, Asrc_l + (size_t)tile_m * CCH,
                  Bsrc_h + (size_t)tile_n * CCH, Bsrc_l + (size_t)tile_n * CCH,
                  CCH, CCH, CCH, sA, sA + 4096, sA + 8192, sA + 12288, acc);

    epi_bf16<true, true, false>(smem, acc, bias + tile_n, nullptr,
                                Oh + (size_t)tile_m * CCH + tile_n,
                                Ol + (size_t)tile_m * CCH + tile_n, CCH);
}

// ---- V projection: D[c][n] = sum_cin Wv[c][cin]*Xt[n][cin] + bv[c], bf16 out
__global__ __launch_bounds__(256) void proj_v_kernel(
    const u16* __restrict__ Wvh, const u16* __restrict__ Tth,
    const float* __restrict__ bvv, u16* __restrict__ Vb) {
    __shared__ __align__(16) char smem[SMEM_BYTES];
    const int z = blockIdx.z;
    const int b = z & 7, i = z >> 3;
    const size_t ib = (size_t)(i * BATCH + b) * HWN * CCH;
    const u16* A = Wvh + (size_t)i * CCH * CCH;
    const u16* B = Tth + ib;
    const int tile_m = blockIdx.y * 128, tile_n = blockIdx.x * 128;

    ACC_INIT(acc)
    u16* sA = (u16*)smem;
    mm_core<false>(A + (size_t)tile_m * CCH, nullptr,
                   B + (size_t)tile_n * CCH, nullptr,
                   CCH, CCH, CCH, sA, nullptr, sA + 4096, nullptr, acc);

    u16* Ov = Vb + (size_t)(i * BATCH + b) * CCH * HWN;
    epi_bf16<false, false, true>(smem, acc, nullptr, bvv + i * CCH + tile_m,
                                 Ov + (size_t)tile_m * HWN + tile_n, nullptr, HWN);
}

// ---- energy: E[n][m] = sum_c Q[n][c]*K[m][c] (split), fp32 out + tile-sum -> means
__global__ __launch_bounds__(256) void gemmE_kernel(
    const u16* __restrict__ Qh, const u16* __restrict__ Ql,
    const u16* __restrict__ Kh, const u16* __restrict__ Kl,
    float* __restrict__ E, float* __restrict__ means, int j, int b0, int Bc) {
    __shared__ __align__(16) char smem[SMEM_BYTES];
    __shared__ float redsum[4];
    const int z = blockIdx.z;
    const int i = z / Bc, bb = z % Bc, b = b0 + bb;
    const size_t offA = (size_t)(i * BATCH + b) * HWN * CCH;
    const size_t offB = (size_t)(j * BATCH + b) * HWN * CCH;
    float* Eo = E + (size_t)(i * Bc + bb) * HWN * HWN;
    const int tile_m = blockIdx.y * 128, tile_n = blockIdx.x * 128;

    ACC_INIT(acc)
    u16* sA = (u16*)smem;
    mm_core<true>(Qh + offA + (size_t)tile_m * CCH, Ql + offA + (size_t)tile_m * CCH,
                  Kh + offB + (size_t)tile_n * CCH, Kl + offB + (size_t)tile_n * CCH,
                  CCH, CCH, CCH, sA, sA + 4096, sA + 8192, sA + 12288, acc);

    const int t = threadIdx.x, w = t >> 6, l = t & 63;
    float tsum = 0.0f;
#pragma unroll
    for (int mi = 0; mi < 4; mi++)
#pragma unroll
        for (int ni = 0; ni < 4; ni++)
#pragma unroll
            for (int r = 0; r < 4; r++) tsum += acc[mi][ni][r];
    tsum = waveReduceSum(tsum);
    if (l == 0) redsum[w] = tsum;
    __syncthreads();
    if (t == 0) atomicAdd(&means[i * 2 + j], redsum[0] + redsum[1] + redsum[2] + redsum[3]);

    epi_f32(smem, acc, Eo + (size_t)tile_m * HWN + tile_n, HWN);
}

// ---- row softmax: E fp32 row -> P bf16 row
__global__ __launch_bounds__(256) void softmax_kernel(const float* __restrict__ E,
                                                      u16* __restrict__ P) {
    const float* rowp = E + (size_t)blockIdx.x * HWN;
    u16* pout = P + (size_t)blockIdx.x * HWN;
    const int t = threadIdx.x;
    const float4 v = ((const float4*)rowp)[t];
    float mx = fmaxf(fmaxf(v.x, v.y), fmaxf(v.z, v.w));
    mx = waveReduceMax(mx);
    __shared__ float redm[4], reds[4];
    const int lane = t & 63, wid = t >> 6;
    if (lane == 0) redm[wid] = mx;
    __syncthreads();
    mx = fmaxf(fmaxf(redm[0], redm[1]), fmaxf(redm[2], redm[3]));
    const float e0 = __expf(v.x - mx), e1 = __expf(v.y - mx);
    const float e2 = __expf(v.z - mx), e3 = __expf(v.w - mx);
    float s = waveReduceSum(e0 + e1 + e2 + e3);
    if (lane == 0) reds[wid] = s;
    __syncthreads();
    const float inv = 1.0f / (reds[0] + reds[1] + reds[2] + reds[3]);
    uint2 pk;
    pk.x = (u32)f2bf(e0 * inv) | ((u32)f2bf(e1 * inv) << 16);
    pk.y = (u32)f2bf(e2 * inv) | ((u32)f2bf(e3 * inv) << 16);
    *(uint2*)&pout[t * 4] = pk;
}

// ---- out[c][n] = sum_m V[c][m]*(P0[n][m]+P1[n][m]), two mm_core passes, fp32 out
__global__ __launch_bounds__(256) void gemmOut_kernel(
    const u16* __restrict__ Vb, const u16* __restrict__ P0, const u16* __restrict__ P1,
    float* __restrict__ outp, int b0, int Bc) {
    __shared__ __align__(16) char smem[SMEM_BYTES];
    const int z = blockIdx.z;
    const int i = z / Bc, bb = z % Bc, b = b0 + bb;
    const u16* A = Vb + (size_t)(i * BATCH + b) * CCH * HWN;
    const size_t offP = (size_t)(i * Bc + bb) * HWN * HWN;
    float* O = outp + (size_t)(i * BATCH + b) * CCH * HWN;
    const int tile_m = blockIdx.y * 128, tile_n = blockIdx.x * 128;

    ACC_INIT(acc)
    u16* sA = (u16*)smem;
    mm_core<false>(A + (size_t)tile_m * HWN, nullptr,
                   P0 + offP + (size_t)tile_n * HWN, nullptr,
                   HWN, HWN, HWN, sA, nullptr, sA + 4096, nullptr, acc);
    mm_core<false>(A + (size_t)tile_m * HWN, nullptr,
                   P1 + offP + (size_t)tile_n * HWN, nullptr,
                   HWN, HWN, HWN, sA, nullptr, sA + 4096, nullptr, acc);

    epi_f32(smem, acc, O + (size_t)tile_m * HWN + tile_n, HWN);
}

__global__ void alphas_kernel(const float* __restrict__ means, float* __restrict__ outp) {
    if (threadIdx.x != 0) return;
    const float cnt = (float)BATCH * (float)HWN * (float)HWN;
    float m[4];
#pragma unroll
    for (int k = 0; k < 4; k++) m[k] = means[k] / cnt;
#pragma unroll
    for (int i = 0; i < 2; i++) {
        const float a = m[i * 2 + 0], bsc = m[i * 2 + 1];
        const float mx = fmaxf(a, bsc);
        const float ea = __expf(a - mx), eb = __expf(bsc - mx);
        const float inv = 1.0f / (ea + eb);
        outp[i * 2 + 0] = ea * inv;
        outp[i * 2 + 1] = eb * inv;
    }
}

extern "C" void kernel_launch(void* const* d_in, const int* in_sizes, int n_in,
                              void* d_out, int out_size, void* d_ws, size_t ws_size,
                              hipStream_t stream) {
    const float* fsrc = (const float*)d_in[0];
    const float* ftgt = (const float*)d_in[1];
    const float* Wq = (const float*)d_in[2];
    const float* bq = (const float*)d_in[3];
    const float* Wk = (const float*)d_in[4];
    const float* bk = (const float*)d_in[5];
    const float* Wv = (const float*)d_in[6];
    const float* bv = (const float*)d_in[7];
    float* outp = (float*)d_out;

    const size_t SZ_ACT = (size_t)NUMH * BATCH * HWN * CCH * 2;  // 16 MiB bf16
    const size_t SZ_W = (size_t)NUMH * CCH * CCH * 2;            // 1 MiB bf16
    char* w = (char*)d_ws;
    u16* Qh = (u16*)w; w += SZ_ACT;
    u16* Ql = (u16*)w; w += SZ_ACT;
    u16* Kh = (u16*)w; w += SZ_ACT;
    u16* Kl = (u16*)w; w += SZ_ACT;
    u16* Vb = (u16*)w; w += SZ_ACT;
    u16* Wqh = (u16*)w; w += SZ_W;
    u16* Wql = (u16*)w; w += SZ_W;
    u16* Wkh = (u16*)w; w += SZ_W;
    u16* Wkl = (u16*)w; w += SZ_W;
    u16* Wvh = (u16*)w; w += SZ_W;
    float* means = (float*)w; w += 64;
    char* region = w;  // transpose buffers live here early; E/P0/P1 overlay later
    u16* Tth = (u16*)region;
    u16* Ttl = (u16*)(region + SZ_ACT);
    u16* Sth = (u16*)(region + 2 * SZ_ACT);
    u16* Stl = (u16*)(region + 3 * SZ_ACT);

    const size_t base_used = (size_t)(region - (char*)d_ws);
    int Bc = 8;
    while (Bc > 1) {
        const size_t tile = (size_t)NUMH * Bc * HWN * HWN;
        size_t need = tile * 4 + 2 * tile * 2;   // E fp32 + P0/P1 bf16
        size_t tneed = need > 4 * SZ_ACT ? need : 4 * SZ_ACT;
        if (base_used + tneed <= ws_size) break;
        Bc >>= 1;
    }
    const size_t tile = (size_t)NUMH * Bc * HWN * HWN;
    float* E = (float*)region;
    u16* P0 = (u16*)(region + tile * 4);
    u16* P1 = (u16*)(region + tile * 4 + tile * 2);

    zero_means_kernel<<<1, 64, 0, stream>>>(means);
    convw_kernel<<<512, 256, 0, stream>>>(Wq, Wk, Wv, Wqh, Wql, Wkh, Wkl, Wvh);
    tsplit_kernel<<<dim3(16, 8, 32), 256, 0, stream>>>(ftgt, fsrc, Tth, Ttl, Sth, Stl);
    proj_qk_kernel<<<dim3(4, 8, 32), 256, 0, stream>>>(Tth, Ttl, Sth, Stl,
                                                       Wqh, Wql, Wkh, Wkl, bq, bk,
                                                       Qh, Ql, Kh, Kl);
    proj_v_kernel<<<dim3(8, 4, 16), 256, 0, stream>>>(Wvh, Tth, bv, Vb);

    const int nch = BATCH / Bc;
    for (int ch = 0; ch < nch; ch++) {
        const int b0 = ch * Bc;
        gemmE_kernel<<<dim3(8, 8, NUMH * Bc), 256, 0, stream>>>(Qh, Ql, Kh, Kl, E, means, 0, b0, Bc);
        softmax_kernel<<<NUMH * Bc * HWN, 256, 0, stream>>>(E, P0);
        gemmE_kernel<<<dim3(8, 8, NUMH * Bc), 256, 0, stream>>>(Qh, Ql, Kh, Kl, E, means, 1, b0, Bc);
        softmax_kernel<<<NUMH * Bc * HWN, 256, 0, stream>>>(E, P1);
        gemmOut_kernel<<<dim3(8, 4, NUMH * Bc), 256, 0, stream>>>(Vb, P0, P1, outp, b0, Bc);
    }
    alphas_kernel<<<1, 1, 0, stream>>>(means, outp + (out_size - 4));
}

// Round 4
// 254.924 us; speedup vs baseline: 5.1897x; 1.4155x over previous
//
#include <hip/hip_runtime.h>

#define NUMH 2
#define BATCH 8
#define CCH 512
#define HWN 1024

typedef unsigned short u16;
typedef unsigned int u32;
typedef _Float16 f16;
typedef __attribute__((ext_vector_type(8))) _Float16 f16x8;
typedef __attribute__((ext_vector_type(4))) float f32x4;

__device__ __forceinline__ u16 f2h(float x) {
    union { f16 h; u16 u; } cv;
    cv.h = (f16)x;
    return cv.u;
}
__device__ __forceinline__ float h2f(u16 u) {
    union { u16 u; f16 h; } cv;
    cv.u = u;
    return (float)cv.h;
}

__device__ __forceinline__ float waveReduceSum(float v) {
#pragma unroll
    for (int off = 32; off > 0; off >>= 1) v += __shfl_xor(v, off);
    return v;
}
__device__ __forceinline__ float waveReduceMax(float v) {
#pragma unroll
    for (int off = 32; off > 0; off >>= 1) v = fmaxf(v, __shfl_xor(v, off));
    return v;
}

__global__ void zero_means_kernel(float* means) {
    if (threadIdx.x < 4) means[threadIdx.x] = 0.0f;
}

// ---- stage a [128 rows][32 k] fp16 tile into an 8 KiB LDS array via global_load_lds.
// 16B-chunk XOR swizzle: physical slot p holds logical (n=p>>2, k4=(p&3)^((n>>1)&3)).
__device__ __forceinline__ void stage_tile(const u16* __restrict__ src, int ld, int k0,
                                           u16* lds_arr, int w, int l) {
#pragma unroll
    for (int inst = 0; inst < 2; inst++) {
        const int p = w * 128 + inst * 64 + l;
        const int n = p >> 2;
        const int k4 = (p & 3) ^ ((n >> 1) & 3);
        const u16* g = src + n * ld + k0 + k4 * 8;
        u16* lp = lds_arr + (w * 128 + inst * 64) * 8;  // wave-uniform; lane adds l*16B
        __builtin_amdgcn_global_load_lds(
            (const __attribute__((address_space(1))) u32*)g,
            (__attribute__((address_space(3))) u32*)lp, 16, 0, 0);
    }
}

__device__ __forceinline__ f16x8 frag_ld(const u16* lds_arr, int row, int kq) {
    const int slot = row * 4 + (kq ^ ((row >> 1) & 3));
    return *(const f16x8*)(lds_arr + slot * 8);
}

// ---- MFMA core: D[128][128] tile, A=[rows][K] fp16, B=[cols][K] fp16,
// D[r][c] = sum_k A[r][k]*B[c][k].
__device__ __forceinline__ void mm_core(const u16* __restrict__ A, const u16* __restrict__ B,
                                        int K, int ldA, int ldB,
                                        u16* sA, u16* sB, f32x4 acc[4][4]) {
    const int t = threadIdx.x, w = t >> 6, l = t & 63;
    const int wr = w >> 1, wc = w & 1;
    const int fr = l & 15, kq = l >> 4;
    for (int k0 = 0; k0 < K; k0 += 32) {
        __syncthreads();
        stage_tile(A, ldA, k0, sA, w, l);
        stage_tile(B, ldB, k0, sB, w, l);
        __syncthreads();
        f16x8 a[4], b[4];
#pragma unroll
        for (int mi = 0; mi < 4; mi++) a[mi] = frag_ld(sA, wr * 64 + mi * 16 + fr, kq);
#pragma unroll
        for (int ni = 0; ni < 4; ni++) b[ni] = frag_ld(sB, wc * 64 + ni * 16 + fr, kq);
#pragma unroll
        for (int mi = 0; mi < 4; mi++)
#pragma unroll
            for (int ni = 0; ni < 4; ni++)
                acc[mi][ni] = __builtin_amdgcn_mfma_f32_16x16x32_f16(a[mi], b[ni], acc[mi][ni], 0, 0, 0);
    }
}

#define ACC_INIT(acc)                                         \
    f32x4 acc[4][4];                                          \
    _Pragma("unroll") for (int mi_ = 0; mi_ < 4; mi_++)       \
    _Pragma("unroll") for (int ni_ = 0; ni_ < 4; ni_++)       \
        acc[mi_][ni_] = (f32x4){0.f, 0.f, 0.f, 0.f};

#define SMEM_BYTES 33792

// ---- epilogue: 128x128 fp16 tile via LDS assembly -> coalesced 16B stores
template<bool BCOL, bool BROW>
__device__ __forceinline__ void epi_h16(char* smem, const f32x4 acc[4][4],
                                        const float* biasCol, const float* biasRow,
                                        u16* O, int ldO) {
    const int t = threadIdx.x, w = t >> 6, l = t & 63;
    const int wr = w >> 1, wc = w & 1, fr = l & 15, fq = l >> 4;
    u16* sb16 = (u16*)smem;   // [128][132]
    u32* sb32 = (u32*)smem;   // [128][66]
    __syncthreads();
#pragma unroll
    for (int ni = 0; ni < 4; ni++) {
        const int col = wc * 64 + ni * 16 + fr;
        const float bc = BCOL ? biasCol[col] : 0.0f;
#pragma unroll
        for (int mi = 0; mi < 4; mi++)
#pragma unroll
            for (int r = 0; r < 4; r++) {
                const int row = wr * 64 + mi * 16 + fq * 4 + r;
                const float v = acc[mi][ni][r] + bc + (BROW ? biasRow[row] : 0.0f);
                sb16[row * 132 + col] = f2h(v);
            }
    }
    __syncthreads();
#pragma unroll
    for (int it = 0; it < 8; it++) {
        const int idx = it * 256 + t;       // 128 rows * 16 chunks of 16B
        const int rr = idx >> 4, ch = idx & 15;
        const uint4 v4 = *(const uint4*)&sb32[rr * 66 + ch * 4];
        *(uint4*)&O[(size_t)rr * ldO + ch * 8] = v4;
    }
}

// ---- epilogue: 128x128 fp32 tile via LDS assembly (two row-halves) -> coalesced stores
__device__ __forceinline__ void epi_f32(char* smem, const f32x4 acc[4][4],
                                        float* O, int ldO) {
    const int t = threadIdx.x, w = t >> 6, l = t & 63;
    const int wr = w >> 1, wc = w & 1, fr = l & 15, fq = l >> 4;
    float* sf = (float*)smem;  // [64][132]
#pragma unroll
    for (int half = 0; half < 2; half++) {
        __syncthreads();
        if (wr == half) {
#pragma unroll
            for (int ni = 0; ni < 4; ni++) {
                const int col = wc * 64 + ni * 16 + fr;
#pragma unroll
                for (int mi = 0; mi < 4; mi++)
#pragma unroll
                    for (int r = 0; r < 4; r++) {
                        const int rl = mi * 16 + fq * 4 + r;
                        sf[rl * 132 + col] = acc[mi][ni][r];
                    }
            }
        }
        __syncthreads();
#pragma unroll
        for (int it = 0; it < 8; it++) {
            const int idx = it * 256 + t;       // 64 rows * 32 chunks of 16B
            const int rr = idx >> 5, ch = idx & 31;
            const float4 v4 = *(const float4*)&sf[rr * 132 + ch * 4];
            *(float4*)&O[(size_t)(half * 64 + rr) * ldO + ch * 4] = v4;
        }
    }
}

// ---- transpose: X fp32 [ib][C][HW]  ->  Xt fp16 [ib][HW][C]
__global__ __launch_bounds__(256) void tconv_kernel(
    const float* __restrict__ tgt, const float* __restrict__ src,
    u16* __restrict__ Tt, u16* __restrict__ St) {
    __shared__ float s[64][65];
    const int z = blockIdx.z;
    const int ib = z & 15;
    const float* X = (z >> 4 ? src : tgt) + (size_t)ib * CCH * HWN;
    u16* O = (z >> 4 ? St : Tt) + (size_t)ib * HWN * CCH;
    const int n0 = blockIdx.x * 64, c0 = blockIdx.y * 64;
    const int t = threadIdx.x;
    {
        const int cc = t >> 4, nch = (t & 15) * 4;
#pragma unroll
        for (int r = 0; r < 4; r++) {
            const float4 v = *(const float4*)&X[(size_t)(c0 + cc + r * 16) * HWN + n0 + nch];
            s[cc + r * 16][nch + 0] = v.x;
            s[cc + r * 16][nch + 1] = v.y;
            s[cc + r * 16][nch + 2] = v.z;
            s[cc + r * 16][nch + 3] = v.w;
        }
    }
    __syncthreads();
    const int nl = t >> 2;            // local row n (0..63)
    const int cb = (t & 3) * 16;      // col chunk base
    __attribute__((aligned(16))) u16 hbuf[16];
#pragma unroll
    for (int cc = 0; cc < 16; cc++) hbuf[cc] = f2h(s[cb + cc][nl]);
    const size_t orow = (size_t)(n0 + nl) * CCH + c0 + cb;
    *(uint4*)&O[orow + 0] = *(const uint4*)&hbuf[0];
    *(uint4*)&O[orow + 8] = *(const uint4*)&hbuf[8];
}

// ---- weights fp32 -> fp16
__global__ __launch_bounds__(256) void convw_kernel(
    const float* __restrict__ Wq, const float* __restrict__ Wk, const float* __restrict__ Wv,
    u16* __restrict__ Wqh, u16* __restrict__ Wkh, u16* __restrict__ Wvh) {
    const int idx = (blockIdx.x * 256 + threadIdx.x) * 4;  // over NUMH*C*C = 524288
    {
        const float4 v = *(const float4*)&Wq[idx];
        uint2 h = {(u32)f2h(v.x) | ((u32)f2h(v.y) << 16), (u32)f2h(v.z) | ((u32)f2h(v.w) << 16)};
        *(uint2*)&Wqh[idx] = h;
    }
    {
        const float4 v = *(const float4*)&Wk[idx];
        uint2 h = {(u32)f2h(v.x) | ((u32)f2h(v.y) << 16), (u32)f2h(v.z) | ((u32)f2h(v.w) << 16)};
        *(uint2*)&Wkh[idx] = h;
    }
    {
        const float4 v = *(const float4*)&Wv[idx];
        uint2 h = {(u32)f2h(v.x) | ((u32)f2h(v.y) << 16), (u32)f2h(v.z) | ((u32)f2h(v.w) << 16)};
        *(uint2*)&Wvh[idx] = h;
    }
}

// ---- Q/K projection: D[n][o] = sum_c Xt[n][c]*W[o][c] + bias[o]
__global__ __launch_bounds__(256) void proj_qk_kernel(
    const u16* __restrict__ Tt, const u16* __restrict__ St,
    const u16* __restrict__ Wqh, const u16* __restrict__ Wkh,
    const float* __restrict__ bq, const float* __restrict__ bk,
    u16* __restrict__ Qp, u16* __restrict__ Kp) {
    __shared__ __align__(16) char smem[SMEM_BYTES];
    const int z = blockIdx.z;
    const int b = z & 7, i = (z >> 3) & 1, p = z >> 4;
    const size_t ib = (size_t)(i * BATCH + b) * HWN * CCH;
    const u16* A = (p ? St : Tt) + ib;
    const u16* B = (p ? Wkh : Wqh) + (size_t)i * CCH * CCH;
    const float* bias = (p ? bk : bq) + i * CCH;
    u16* O = (p ? Kp : Qp) + ib;
    const int tile_m = blockIdx.y * 128, tile_n = blockIdx.x * 128;

    ACC_INIT(acc)
    u16* sA = (u16*)smem;
    mm_core(A + (size_t)tile_m * CCH, B + (size_t)tile_n * CCH,
            CCH, CCH, CCH, sA, sA + 4096, acc);

    epi_h16<true, false>(smem, acc, bias + tile_n, nullptr,
                         O + (size_t)tile_m * CCH + tile_n, CCH);
}

// ---- V projection: D[c][n] = sum_cin Wv[c][cin]*Xt[n][cin] + bv[c]
__global__ __launch_bounds__(256) void proj_v_kernel(
    const u16* __restrict__ Wvh, const u16* __restrict__ Tt,
    const float* __restrict__ bvv, u16* __restrict__ Vb) {
    __shared__ __align__(16) char smem[SMEM_BYTES];
    const int z = blockIdx.z;
    const int b = z & 7, i = z >> 3;
    const size_t ib = (size_t)(i * BATCH + b) * HWN * CCH;
    const u16* A = Wvh + (size_t)i * CCH * CCH;
    const u16* B = Tt + ib;
    const int tile_m = blockIdx.y * 128, tile_n = blockIdx.x * 128;

    ACC_INIT(acc)
    u16* sA = (u16*)smem;
    mm_core(A + (size_t)tile_m * CCH, B + (size_t)tile_n * CCH,
            CCH, CCH, CCH, sA, sA + 4096, acc);

    u16* Ov = Vb + (size_t)(i * BATCH + b) * CCH * HWN;
    epi_h16<false, true>(smem, acc, nullptr, bvv + i * CCH + tile_m,
                         Ov + (size_t)tile_m * HWN + tile_n, HWN);
}

// ---- energy: E[n][m] = sum_c Q[n][c]*K[m][c], fp16 out + tile-sum -> means
__global__ __launch_bounds__(256) void gemmE_kernel(
    const u16* __restrict__ Qp, const u16* __restrict__ Kp,
    u16* __restrict__ E, float* __restrict__ means, int j, int b0, int Bc) {
    __shared__ __align__(16) char smem[SMEM_BYTES];
    __shared__ float redsum[4];
    const int z = blockIdx.z;
    const int i = z / Bc, bb = z % Bc, b = b0 + bb;
    const size_t offA = (size_t)(i * BATCH + b) * HWN * CCH;
    const size_t offB = (size_t)(j * BATCH + b) * HWN * CCH;
    u16* Eo = E + (size_t)(i * Bc + bb) * HWN * HWN;
    const int tile_m = blockIdx.y * 128, tile_n = blockIdx.x * 128;

    ACC_INIT(acc)
    u16* sA = (u16*)smem;
    mm_core(Qp + offA + (size_t)tile_m * CCH, Kp + offB + (size_t)tile_n * CCH,
            CCH, CCH, CCH, sA, sA + 4096, acc);

    const int t = threadIdx.x, w = t >> 6, l = t & 63;
    float tsum = 0.0f;
#pragma unroll
    for (int mi = 0; mi < 4; mi++)
#pragma unroll
        for (int ni = 0; ni < 4; ni++)
#pragma unroll
            for (int r = 0; r < 4; r++) tsum += acc[mi][ni][r];
    tsum = waveReduceSum(tsum);
    if (l == 0) redsum[w] = tsum;
    __syncthreads();
    if (t == 0) atomicAdd(&means[i * 2 + j], redsum[0] + redsum[1] + redsum[2] + redsum[3]);

    epi_h16<false, false>(smem, acc, nullptr, nullptr,
                          Eo + (size_t)tile_m * HWN + tile_n, HWN);
}

// ---- row softmax: E fp16 row -> P fp16 row
__global__ __launch_bounds__(256) void softmax_kernel(const u16* __restrict__ E,
                                                      u16* __restrict__ P) {
    const u16* rowp = E + (size_t)blockIdx.x * HWN;
    u16* pout = P + (size_t)blockIdx.x * HWN;
    const int t = threadIdx.x;
    const uint2 hv = *(const uint2*)&rowp[t * 4];
    float v0 = h2f((u16)(hv.x & 0xffff)), v1 = h2f((u16)(hv.x >> 16));
    float v2 = h2f((u16)(hv.y & 0xffff)), v3 = h2f((u16)(hv.y >> 16));
    float mx = fmaxf(fmaxf(v0, v1), fmaxf(v2, v3));
    mx = waveReduceMax(mx);
    __shared__ float redm[4], reds[4];
    const int lane = t & 63, wid = t >> 6;
    if (lane == 0) redm[wid] = mx;
    __syncthreads();
    mx = fmaxf(fmaxf(redm[0], redm[1]), fmaxf(redm[2], redm[3]));
    const float e0 = __expf(v0 - mx), e1 = __expf(v1 - mx);
    const float e2 = __expf(v2 - mx), e3 = __expf(v3 - mx);
    float s = waveReduceSum(e0 + e1 + e2 + e3);
    if (lane == 0) reds[wid] = s;
    __syncthreads();
    const float inv = 1.0f / (reds[0] + reds[1] + reds[2] + reds[3]);
    uint2 pk;
    pk.x = (u32)f2h(e0 * inv) | ((u32)f2h(e1 * inv) << 16);
    pk.y = (u32)f2h(e2 * inv) | ((u32)f2h(e3 * inv) << 16);
    *(uint2*)&pout[t * 4] = pk;
}

// ---- out[c][n] = sum_m V[c][m]*(P0[n][m]+P1[n][m]), two mm_core passes, fp32 out
__global__ __launch_bounds__(256) void gemmOut_kernel(
    const u16* __restrict__ Vb, const u16* __restrict__ P0, const u16* __restrict__ P1,
    float* __restrict__ outp, int b0, int Bc) {
    __shared__ __align__(16) char smem[SMEM_BYTES];
    const int z = blockIdx.z;
    const int i = z / Bc, bb = z % Bc, b = b0 + bb;
    const u16* A = Vb + (size_t)(i * BATCH + b) * CCH * HWN;
    const size_t offP = (size_t)(i * Bc + bb) * HWN * HWN;
    float* O = outp + (size_t)(i * BATCH + b) * CCH * HWN;
    const int tile_m = blockIdx.y * 128, tile_n = blockIdx.x * 128;

    ACC_INIT(acc)
    u16* sA = (u16*)smem;
    mm_core(A + (size_t)tile_m * HWN, P0 + offP + (size_t)tile_n * HWN,
            HWN, HWN, HWN, sA, sA + 4096, acc);
    mm_core(A + (size_t)tile_m * HWN, P1 + offP + (size_t)tile_n * HWN,
            HWN, HWN, HWN, sA, sA + 4096, acc);

    epi_f32(smem, acc, O + (size_t)tile_m * HWN + tile_n, HWN);
}

__global__ void alphas_kernel(const float* __restrict__ means, float* __restrict__ outp) {
    if (threadIdx.x != 0) return;
    const float cnt = (float)BATCH * (float)HWN * (float)HWN;
    float m[4];
#pragma unroll
    for (int k = 0; k < 4; k++) m[k] = means[k] / cnt;
#pragma unroll
    for (int i = 0; i < 2; i++) {
        const float a = m[i * 2 + 0], bsc = m[i * 2 + 1];
        const float mx = fmaxf(a, bsc);
        const float ea = __expf(a - mx), eb = __expf(bsc - mx);
        const float inv = 1.0f / (ea + eb);
        outp[i * 2 + 0] = ea * inv;
        outp[i * 2 + 1] = eb * inv;
    }
}

extern "C" void kernel_launch(void* const* d_in, const int* in_sizes, int n_in,
                              void* d_out, int out_size, void* d_ws, size_t ws_size,
                              hipStream_t stream) {
    const float* fsrc = (const float*)d_in[0];
    const float* ftgt = (const float*)d_in[1];
    const float* Wq = (const float*)d_in[2];
    const float* bq = (const float*)d_in[3];
    const float* Wk = (const float*)d_in[4];
    const float* bk = (const float*)d_in[5];
    const float* Wv = (const float*)d_in[6];
    const float* bv = (const float*)d_in[7];
    float* outp = (float*)d_out;

    const size_t SZ_ACT = (size_t)NUMH * BATCH * HWN * CCH * 2;  // 16 MiB fp16
    const size_t SZ_W = (size_t)NUMH * CCH * CCH * 2;            // 1 MiB fp16
    char* w = (char*)d_ws;
    u16* Qp = (u16*)w; w += SZ_ACT;
    u16* Kp = (u16*)w; w += SZ_ACT;
    u16* Vb = (u16*)w; w += SZ_ACT;
    u16* Wqh = (u16*)w; w += SZ_W;
    u16* Wkh = (u16*)w; w += SZ_W;
    u16* Wvh = (u16*)w; w += SZ_W;
    float* means = (float*)w; w += 64;
    char* region = w;  // transpose buffers live here early; E/P0/P1 overlay later
    u16* Tt = (u16*)region;
    u16* St = (u16*)(region + SZ_ACT);

    const size_t base_used = (size_t)(region - (char*)d_ws);
    int Bc = 8;
    while (Bc > 1) {
        const size_t tile = (size_t)NUMH * Bc * HWN * HWN;
        size_t need = 3 * tile * 2;              // E + P0 + P1, all fp16
        size_t tneed = need > 2 * SZ_ACT ? need : 2 * SZ_ACT;
        if (base_used + tneed <= ws_size) break;
        Bc >>= 1;
    }
    const size_t tile = (size_t)NUMH * Bc * HWN * HWN;
    u16* E = (u16*)region;
    u16* P0 = (u16*)(region + tile * 2);
    u16* P1 = (u16*)(region + tile * 4);

    zero_means_kernel<<<1, 64, 0, stream>>>(means);
    convw_kernel<<<512, 256, 0, stream>>>(Wq, Wk, Wv, Wqh, Wkh, Wvh);
    tconv_kernel<<<dim3(16, 8, 32), 256, 0, stream>>>(ftgt, fsrc, Tt, St);
    proj_qk_kernel<<<dim3(4, 8, 32), 256, 0, stream>>>(Tt, St, Wqh, Wkh, bq, bk, Qp, Kp);
    proj_v_kernel<<<dim3(8, 4, 16), 256, 0, stream>>>(Wvh, Tt, bv, Vb);

    const int nch = BATCH / Bc;
    for (int ch = 0; ch < nch; ch++) {
        const int b0 = ch * Bc;
        gemmE_kernel<<<dim3(8, 8, NUMH * Bc), 256, 0, stream>>>(Qp, Kp, E, means, 0, b0, Bc);
        softmax_kernel<<<NUMH * Bc * HWN, 256, 0, stream>>>(E, P0);
        gemmE_kernel<<<dim3(8, 8, NUMH * Bc), 256, 0, stream>>>(Qp, Kp, E, means, 1, b0, Bc);
        softmax_kernel<<<NUMH * Bc * HWN, 256, 0, stream>>>(E, P1);
        gemmOut_kernel<<<dim3(8, 4, NUMH * Bc), 256, 0, stream>>>(Vb, P0, P1, outp, b0, Bc);
    }
    alphas_kernel<<<1, 1, 0, stream>>>(means, outp + (out_size - 4));
}

// Round 6
// 200.982 us; speedup vs baseline: 6.5826x; 1.2684x over previous
//
#include <hip/hip_runtime.h>

#define NUMH 2
#define BATCH 8
#define CCH 512
#define HWN 1024

typedef unsigned short u16;
typedef unsigned int u32;
typedef _Float16 f16;
typedef __attribute__((ext_vector_type(8))) _Float16 f16x8;
typedef __attribute__((ext_vector_type(8))) short bf16x8;
typedef __attribute__((ext_vector_type(4))) float f32x4;

__device__ __forceinline__ u16 f2h(float x) {
    union { f16 h; u16 u; } cv;
    cv.h = (f16)x;
    return cv.u;
}
__device__ __forceinline__ u16 f2bf(float x) {
    u32 u = __float_as_uint(x);
    return (u16)((u + 0x7fffu + ((u >> 16) & 1u)) >> 16);
}
__device__ __forceinline__ float bf2f(u16 h) { return __uint_as_float(((u32)h) << 16); }

__device__ __forceinline__ float waveReduceSum(float v) {
#pragma unroll
    for (int off = 32; off > 0; off >>= 1) v += __shfl_xor(v, off);
    return v;
}

__global__ void zero_means_kernel(float* means) {
    if (threadIdx.x < 4) means[threadIdx.x] = 0.0f;
}
__global__ void zero_rs_kernel(float* rs, int n) {
    const int i = blockIdx.x * 256 + threadIdx.x;
    if (i < n) rs[i] = 0.0f;
}

// ---- stage a [128 rows][32 k] 16-bit tile into an 8 KiB LDS array via global_load_lds.
// 16B-chunk XOR swizzle: physical slot p holds logical (n=p>>2, k4=(p&3)^((n>>1)&3)).
__device__ __forceinline__ void stage_tile(const u16* __restrict__ src, int ld, int k0,
                                           u16* lds_arr, int w, int l) {
#pragma unroll
    for (int inst = 0; inst < 2; inst++) {
        const int p = w * 128 + inst * 64 + l;
        const int n = p >> 2;
        const int k4 = (p & 3) ^ ((n >> 1) & 3);
        const u16* g = src + n * ld + k0 + k4 * 8;
        u16* lp = lds_arr + (w * 128 + inst * 64) * 8;  // wave-uniform; lane adds l*16B
        __builtin_amdgcn_global_load_lds(
            (const __attribute__((address_space(1))) u32*)g,
            (__attribute__((address_space(3))) u32*)lp, 16, 0, 0);
    }
}

// ---- one 32-k MFMA block (16 MFMA) from a staged LDS pair
template<bool BF>
__device__ __forceinline__ void mfma_block(const u16* sA, const u16* sB,
                                           int wr, int wc, int fr, int kq, f32x4 acc[4][4]) {
#define SLOT(row) (((row) * 4 + ((kq) ^ (((row) >> 1) & 3))) * 8)
    if constexpr (BF) {
        bf16x8 a[4], b[4];
#pragma unroll
        for (int mi = 0; mi < 4; mi++) a[mi] = *(const bf16x8*)(sA + SLOT(wr * 64 + mi * 16 + fr));
#pragma unroll
        for (int ni = 0; ni < 4; ni++) b[ni] = *(const bf16x8*)(sB + SLOT(wc * 64 + ni * 16 + fr));
#pragma unroll
        for (int mi = 0; mi < 4; mi++)
#pragma unroll
            for (int ni = 0; ni < 4; ni++)
                acc[mi][ni] = __builtin_amdgcn_mfma_f32_16x16x32_bf16(a[mi], b[ni], acc[mi][ni], 0, 0, 0);
    } else {
        f16x8 a[4], b[4];
#pragma unroll
        for (int mi = 0; mi < 4; mi++) a[mi] = *(const f16x8*)(sA + SLOT(wr * 64 + mi * 16 + fr));
#pragma unroll
        for (int ni = 0; ni < 4; ni++) b[ni] = *(const f16x8*)(sB + SLOT(wc * 64 + ni * 16 + fr));
#pragma unroll
        for (int mi = 0; mi < 4; mi++)
#pragma unroll
            for (int ni = 0; ni < 4; ni++)
                acc[mi][ni] = __builtin_amdgcn_mfma_f32_16x16x32_f16(a[mi], b[ni], acc[mi][ni], 0, 0, 0);
    }
#undef SLOT
}

// ---- MFMA core: D[128][128] tile, A=[rows][K], B=[cols][K], BK=64 (32 MFMA per barrier)
template<bool BF>
__device__ __forceinline__ void mm_core(const u16* __restrict__ A, const u16* __restrict__ B,
                                        int K, int ldA, int ldB, u16* s, f32x4 acc[4][4]) {
    const int t = threadIdx.x, w = t >> 6, l = t & 63;
    const int wr = w >> 1, wc = w & 1, fr = l & 15, kq = l >> 4;
    u16 *sA0 = s, *sA1 = s + 4096, *sB0 = s + 8192, *sB1 = s + 12288;
    for (int k0 = 0; k0 < K; k0 += 64) {
        __syncthreads();
        stage_tile(A, ldA, k0, sA0, w, l);
        stage_tile(A, ldA, k0 + 32, sA1, w, l);
        stage_tile(B, ldB, k0, sB0, w, l);
        stage_tile(B, ldB, k0 + 32, sB1, w, l);
        __syncthreads();
        mfma_block<BF>(sA0, sB0, wr, wc, fr, kq, acc);
        mfma_block<BF>(sA1, sB1, wr, wc, fr, kq, acc);
    }
}

#define ACC_INIT(acc)                                         \
    f32x4 acc[4][4];                                          \
    _Pragma("unroll") for (int mi_ = 0; mi_ < 4; mi_++)       \
    _Pragma("unroll") for (int ni_ = 0; ni_ < 4; ni_++)       \
        acc[mi_][ni_] = (f32x4){0.f, 0.f, 0.f, 0.f};

#define SMEM_BYTES 33792

// ---- epilogue: 128x128 16-bit tile via LDS assembly -> coalesced 16B stores
// BF: store bf16 else fp16.
template<bool BF, bool BCOL, bool BROW>
__device__ __forceinline__ void epi_h16(char* smem, const f32x4 acc[4][4],
                                        const float* biasCol, const float* biasRow,
                                        u16* O, int ldO) {
    const int t = threadIdx.x, w = t >> 6, l = t & 63;
    const int wr = w >> 1, wc = w & 1, fr = l & 15, fq = l >> 4;
    u16* sb16 = (u16*)smem;   // [128][132]
    u32* sb32 = (u32*)smem;   // [128][66]
    __syncthreads();
#pragma unroll
    for (int ni = 0; ni < 4; ni++) {
        const int col = wc * 64 + ni * 16 + fr;
        const float bc = BCOL ? biasCol[col] : 0.0f;
#pragma unroll
        for (int mi = 0; mi < 4; mi++)
#pragma unroll
            for (int r = 0; r < 4; r++) {
                const int row = wr * 64 + mi * 16 + fq * 4 + r;
                const float v = acc[mi][ni][r] + bc + (BROW ? biasRow[row] : 0.0f);
                sb16[row * 132 + col] = BF ? f2bf(v) : f2h(v);
            }
    }
    __syncthreads();
#pragma unroll
    for (int it = 0; it < 8; it++) {
        const int idx = it * 256 + t;       // 128 rows * 16 chunks of 16B
        const int rr = idx >> 4, ch = idx & 15;
        const uint4 v4 = *(const uint4*)&sb32[rr * 66 + ch * 4];
        *(uint4*)&O[(size_t)rr * ldO + ch * 8] = v4;
    }
}

// ---- epilogue: 128x128 fp32 tile, per-col scale, via LDS assembly -> coalesced stores
template<bool SCALE>
__device__ __forceinline__ void epi_f32(char* smem, const f32x4 acc[4][4],
                                        const float* ls, float* O, int ldO) {
    const int t = threadIdx.x, w = t >> 6, l = t & 63;
    const int wr = w >> 1, wc = w & 1, fr = l & 15, fq = l >> 4;
    float* sf = (float*)smem;  // [64][132]
#pragma unroll
    for (int half = 0; half < 2; half++) {
        __syncthreads();
        if (wr == half) {
#pragma unroll
            for (int ni = 0; ni < 4; ni++) {
                const int col = wc * 64 + ni * 16 + fr;
                const float inv = SCALE ? 1.0f / ls[col] : 1.0f;
#pragma unroll
                for (int mi = 0; mi < 4; mi++)
#pragma unroll
                    for (int r = 0; r < 4; r++) {
                        const int rl = mi * 16 + fq * 4 + r;
                        sf[rl * 132 + col] = acc[mi][ni][r] * inv;
                    }
            }
        }
        __syncthreads();
#pragma unroll
        for (int it = 0; it < 8; it++) {
            const int idx = it * 256 + t;       // 64 rows * 32 chunks of 16B
            const int rr = idx >> 5, ch = idx & 31;
            const float4 v4 = *(const float4*)&sf[rr * 132 + ch * 4];
            *(float4*)&O[(size_t)(half * 64 + rr) * ldO + ch * 4] = v4;
        }
    }
}

// ---- transpose: X fp32 [ib][C][HW]  ->  Xt fp16 [ib][HW][C]
__global__ __launch_bounds__(256) void tconv_kernel(
    const float* __restrict__ tgt, const float* __restrict__ src,
    u16* __restrict__ Tt, u16* __restrict__ St) {
    __shared__ float s[64][65];
    const int z = blockIdx.z;
    const int ib = z & 15;
    const float* X = (z >> 4 ? src : tgt) + (size_t)ib * CCH * HWN;
    u16* O = (z >> 4 ? St : Tt) + (size_t)ib * HWN * CCH;
    const int n0 = blockIdx.x * 64, c0 = blockIdx.y * 64;
    const int t = threadIdx.x;
    {
        const int cc = t >> 4, nch = (t & 15) * 4;
#pragma unroll
        for (int r = 0; r < 4; r++) {
            const float4 v = *(const float4*)&X[(size_t)(c0 + cc + r * 16) * HWN + n0 + nch];
            s[cc + r * 16][nch + 0] = v.x;
            s[cc + r * 16][nch + 1] = v.y;
            s[cc + r * 16][nch + 2] = v.z;
            s[cc + r * 16][nch + 3] = v.w;
        }
    }
    __syncthreads();
    const int nl = t >> 2;            // local row n (0..63)
    const int cb = (t & 3) * 16;      // col chunk base
    __attribute__((aligned(16))) u16 hbuf[16];
#pragma unroll
    for (int cc = 0; cc < 16; cc++) hbuf[cc] = f2h(s[cb + cc][nl]);
    const size_t orow = (size_t)(n0 + nl) * CCH + c0 + cb;
    *(uint4*)&O[orow + 0] = *(const uint4*)&hbuf[0];
    *(uint4*)&O[orow + 8] = *(const uint4*)&hbuf[8];
}

// ---- weights fp32 -> fp16
__global__ __launch_bounds__(256) void convw_kernel(
    const float* __restrict__ Wq, const float* __restrict__ Wk, const float* __restrict__ Wv,
    u16* __restrict__ Wqh, u16* __restrict__ Wkh, u16* __restrict__ Wvh) {
    const int idx = (blockIdx.x * 256 + threadIdx.x) * 4;  // over NUMH*C*C = 524288
    {
        const float4 v = *(const float4*)&Wq[idx];
        uint2 h = {(u32)f2h(v.x) | ((u32)f2h(v.y) << 16), (u32)f2h(v.z) | ((u32)f2h(v.w) << 16)};
        *(uint2*)&Wqh[idx] = h;
    }
    {
        const float4 v = *(const float4*)&Wk[idx];
        uint2 h = {(u32)f2h(v.x) | ((u32)f2h(v.y) << 16), (u32)f2h(v.z) | ((u32)f2h(v.w) << 16)};
        *(uint2*)&Wkh[idx] = h;
    }
    {
        const float4 v = *(const float4*)&Wv[idx];
        uint2 h = {(u32)f2h(v.x) | ((u32)f2h(v.y) << 16), (u32)f2h(v.z) | ((u32)f2h(v.w) << 16)};
        *(uint2*)&Wvh[idx] = h;
    }
}

// ---- Q/K projection: D[n][o] = sum_c Xt[n][c]*W[o][c] + bias[o], fp16 out
__global__ __launch_bounds__(256) void proj_qk_kernel(
    const u16* __restrict__ Tt, const u16* __restrict__ St,
    const u16* __restrict__ Wqh, const u16* __restrict__ Wkh,
    const float* __restrict__ bq, const float* __restrict__ bk,
    u16* __restrict__ Qp, u16* __restrict__ Kp) {
    __shared__ __align__(16) char smem[SMEM_BYTES];
    const int z = blockIdx.z;
    const int b = z & 7, i = (z >> 3) & 1, p = z >> 4;
    const size_t ib = (size_t)(i * BATCH + b) * HWN * CCH;
    const u16* A = (p ? St : Tt) + ib;
    const u16* B = (p ? Wkh : Wqh) + (size_t)i * CCH * CCH;
    const float* bias = (p ? bk : bq) + i * CCH;
    u16* O = (p ? Kp : Qp) + ib;
    const int tile_m = blockIdx.y * 128, tile_n = blockIdx.x * 128;

    ACC_INIT(acc)
    mm_core<false>(A + (size_t)tile_m * CCH, B + (size_t)tile_n * CCH,
                   CCH, CCH, CCH, (u16*)smem, acc);

    epi_h16<false, true, false>(smem, acc, bias + tile_n, nullptr,
                                O + (size_t)tile_m * CCH + tile_n, CCH);
}

// ---- V projection: D[c][n] = sum_cin Wv[c][cin]*Xt[n][cin] + bv[c], bf16 out
__global__ __launch_bounds__(256) void proj_v_kernel(
    const u16* __restrict__ Wvh, const u16* __restrict__ Tt,
    const float* __restrict__ bvv, u16* __restrict__ Vb) {
    __shared__ __align__(16) char smem[SMEM_BYTES];
    const int z = blockIdx.z;
    const int b = z & 7, i = z >> 3;
    const size_t ib = (size_t)(i * BATCH + b) * HWN * CCH;
    const u16* A = Wvh + (size_t)i * CCH * CCH;
    const u16* B = Tt + ib;
    const int tile_m = blockIdx.y * 128, tile_n = blockIdx.x * 128;

    ACC_INIT(acc)
    mm_core<false>(A + (size_t)tile_m * CCH, B + (size_t)tile_n * CCH,
                   CCH, CCH, CCH, (u16*)smem, acc);

    u16* Ov = Vb + (size_t)(i * BATCH + b) * CCH * HWN;
    epi_h16<true, false, true>(smem, acc, nullptr, bvv + i * CCH + tile_m,
                               Ov + (size_t)tile_m * HWN + tile_n, HWN);
}

// ---- energy fused: P~[n][m] = exp(sum_c Q[n][c]*K[m][c]) bf16; rowsum + means atomics
__global__ __launch_bounds__(256) void gemmE_kernel(
    const u16* __restrict__ Qp, const u16* __restrict__ Kp,
    u16* __restrict__ P, float* __restrict__ rs, float* __restrict__ means,
    int b0, int Bc) {
    __shared__ __align__(16) char smem[SMEM_BYTES];
    __shared__ float redsum[4];
    const int z = blockIdx.z;
    const int j = z & 1, ib2 = z >> 1;
    const int i = ib2 / Bc, bb = ib2 % Bc, b = b0 + bb;
    const size_t offA = (size_t)(i * BATCH + b) * HWN * CCH;
    const size_t offB = (size_t)(j * BATCH + b) * HWN * CCH;
    const int tile_m = blockIdx.y * 128, tile_n = blockIdx.x * 128;
    // FIX (round 5): tile origin was missing from Po -> all blocks wrote tile (0,0).
    u16* Po = P + (size_t)(ib2 * 2 + j) * HWN * HWN + (size_t)tile_m * HWN + tile_n;
    float* rsp = rs + (size_t)(ib2 * 2 + j) * HWN;

    ACC_INIT(acc)
    mm_core<false>(Qp + offA + (size_t)tile_m * CCH, Kp + offB + (size_t)tile_n * CCH,
                   CCH, CCH, CCH, (u16*)smem, acc);

    const int t = threadIdx.x, w = t >> 6, l = t & 63;
    const int wr = w >> 1, wc = w & 1, fr = l & 15, fq = l >> 4;
    u16* sb16 = (u16*)smem;   // [128][132]
    u32* sb32 = (u32*)smem;   // [128][66]
    __syncthreads();
    float tsum = 0.0f;
    float rowacc[4][4];
#pragma unroll
    for (int mi = 0; mi < 4; mi++)
#pragma unroll
        for (int r = 0; r < 4; r++) rowacc[mi][r] = 0.0f;
#pragma unroll
    for (int ni = 0; ni < 4; ni++) {
        const int col = wc * 64 + ni * 16 + fr;
#pragma unroll
        for (int mi = 0; mi < 4; mi++)
#pragma unroll
            for (int r = 0; r < 4; r++) {
                const int row = wr * 64 + mi * 16 + fq * 4 + r;
                const float raw = acc[mi][ni][r];
                tsum += raw;
                const u16 eb = f2bf(__expf(raw));
                rowacc[mi][r] += bf2f(eb);   // sum the ROUNDED values
                sb16[row * 132 + col] = eb;
            }
    }
    // means partial (raw E sum)
    tsum = waveReduceSum(tsum);
    if (l == 0) redsum[w] = tsum;
    // per-row exp sums: reduce across the 16 fr lanes, one atomic per row per wave
#pragma unroll
    for (int mi = 0; mi < 4; mi++)
#pragma unroll
        for (int r = 0; r < 4; r++) {
            float v = rowacc[mi][r];
            v += __shfl_xor(v, 1); v += __shfl_xor(v, 2);
            v += __shfl_xor(v, 4); v += __shfl_xor(v, 8);
            if (fr == 0) atomicAdd(&rsp[tile_m + wr * 64 + mi * 16 + fq * 4 + r], v);
        }
    __syncthreads();
    if (t == 0) atomicAdd(&means[i * 2 + j], redsum[0] + redsum[1] + redsum[2] + redsum[3]);
    // coalesced P~ store
#pragma unroll
    for (int it = 0; it < 8; it++) {
        const int idx = it * 256 + t;
        const int rr = idx >> 4, ch = idx & 15;
        const uint4 v4 = *(const uint4*)&sb32[rr * 66 + ch * 4];
        *(uint4*)&Po[(size_t)rr * HWN + ch * 8] = v4;
    }
}

// ---- out[c][n] = (A0*(l1/l0) + A1)/l1 where Aj = sum_m V[c][m]*P~j[n][m]
__global__ __launch_bounds__(256) void gemmOut_kernel(
    const u16* __restrict__ Vb, const u16* __restrict__ P, const float* __restrict__ rs,
    float* __restrict__ outp, int b0, int Bc) {
    __shared__ __align__(16) char smem[SMEM_BYTES];
    const int ib2 = blockIdx.z;
    const int i = ib2 / Bc, bb = ib2 % Bc, b = b0 + bb;
    const u16* A = Vb + (size_t)(i * BATCH + b) * CCH * HWN;
    const u16* P0 = P + (size_t)(ib2 * 2 + 0) * HWN * HWN;
    const u16* P1 = P + (size_t)(ib2 * 2 + 1) * HWN * HWN;
    const float* rs0 = rs + (size_t)(ib2 * 2 + 0) * HWN;
    const float* rs1 = rs + (size_t)(ib2 * 2 + 1) * HWN;
    float* O = outp + (size_t)(i * BATCH + b) * CCH * HWN;
    const int tile_m = blockIdx.y * 128, tile_n = blockIdx.x * 128;
    const int t = threadIdx.x, w = t >> 6, l = t & 63;
    const int wc = w & 1, fr = l & 15;

    ACC_INIT(acc)
    mm_core<true>(A + (size_t)tile_m * HWN, P0 + (size_t)tile_n * HWN,
                  HWN, HWN, HWN, (u16*)smem, acc);
    // rescale: acc *= l1[n]/l0[n] (per output column n)
#pragma unroll
    for (int ni = 0; ni < 4; ni++) {
        const int col = tile_n + wc * 64 + ni * 16 + fr;
        const float sc = rs1[col] / rs0[col];
#pragma unroll
        for (int mi = 0; mi < 4; mi++) acc[mi][ni] *= sc;
    }
    mm_core<true>(A + (size_t)tile_m * HWN, P1 + (size_t)tile_n * HWN,
                  HWN, HWN, HWN, (u16*)smem, acc);

    epi_f32<true>(smem, acc, rs1 + tile_n, O + (size_t)tile_m * HWN + tile_n, HWN);
}

__global__ void alphas_kernel(const float* __restrict__ means, float* __restrict__ outp) {
    if (threadIdx.x != 0) return;
    const float cnt = (float)BATCH * (float)HWN * (float)HWN;
    float m[4];
#pragma unroll
    for (int k = 0; k < 4; k++) m[k] = means[k] / cnt;
#pragma unroll
    for (int i = 0; i < 2; i++) {
        const float a = m[i * 2 + 0], bsc = m[i * 2 + 1];
        const float mx = fmaxf(a, bsc);
        const float ea = __expf(a - mx), eb = __expf(bsc - mx);
        const float inv = 1.0f / (ea + eb);
        outp[i * 2 + 0] = ea * inv;
        outp[i * 2 + 1] = eb * inv;
    }
}

extern "C" void kernel_launch(void* const* d_in, const int* in_sizes, int n_in,
                              void* d_out, int out_size, void* d_ws, size_t ws_size,
                              hipStream_t stream) {
    const float* fsrc = (const float*)d_in[0];
    const float* ftgt = (const float*)d_in[1];
    const float* Wq = (const float*)d_in[2];
    const float* bq = (const float*)d_in[3];
    const float* Wk = (const float*)d_in[4];
    const float* bk = (const float*)d_in[5];
    const float* Wv = (const float*)d_in[6];
    const float* bv = (const float*)d_in[7];
    float* outp = (float*)d_out;

    const size_t SZ_ACT = (size_t)NUMH * BATCH * HWN * CCH * 2;  // 16 MiB 16-bit
    const size_t SZ_W = (size_t)NUMH * CCH * CCH * 2;            // 1 MiB 16-bit
    char* w = (char*)d_ws;
    u16* Qp = (u16*)w; w += SZ_ACT;
    u16* Kp = (u16*)w; w += SZ_ACT;
    u16* Vb = (u16*)w; w += SZ_ACT;
    u16* Wqh = (u16*)w; w += SZ_W;
    u16* Wkh = (u16*)w; w += SZ_W;
    u16* Wvh = (u16*)w; w += SZ_W;
    float* means = (float*)w; w += 64;
    float* rs = (float*)w; w += (size_t)NUMH * BATCH * 2 * HWN * 4;  // rowsums (max Bc)
    char* region = w;  // transpose buffers live here early; P~ overlays later
    u16* Tt = (u16*)region;
    u16* St = (u16*)(region + SZ_ACT);

    const size_t base_used = (size_t)(region - (char*)d_ws);
    int Bc = 8;
    while (Bc > 1) {
        size_t need = (size_t)NUMH * Bc * 2 * HWN * HWN * 2;  // P~ bf16
        size_t tneed = need > 2 * SZ_ACT ? need : 2 * SZ_ACT;
        if (base_used + tneed <= ws_size) break;
        Bc >>= 1;
    }
    u16* P = (u16*)region;
    const int nrs = NUMH * Bc * 2 * HWN;

    zero_means_kernel<<<1, 64, 0, stream>>>(means);
    convw_kernel<<<512, 256, 0, stream>>>(Wq, Wk, Wv, Wqh, Wkh, Wvh);
    tconv_kernel<<<dim3(16, 8, 32), 256, 0, stream>>>(ftgt, fsrc, Tt, St);
    proj_qk_kernel<<<dim3(4, 8, 32), 256, 0, stream>>>(Tt, St, Wqh, Wkh, bq, bk, Qp, Kp);
    proj_v_kernel<<<dim3(8, 4, 16), 256, 0, stream>>>(Wvh, Tt, bv, Vb);

    const int nch = BATCH / Bc;
    for (int ch = 0; ch < nch; ch++) {
        const int b0 = ch * Bc;
        zero_rs_kernel<<<(nrs + 255) / 256, 256, 0, stream>>>(rs, nrs);
        gemmE_kernel<<<dim3(8, 8, NUMH * Bc * 2), 256, 0, stream>>>(Qp, Kp, P, rs, means, b0, Bc);
        gemmOut_kernel<<<dim3(8, 4, NUMH * Bc), 256, 0, stream>>>(Vb, P, rs, outp, b0, Bc);
    }
    alphas_kernel<<<1, 1, 0, stream>>>(means, outp + (out_size - 4));
}